// Round 18
// baseline (315.869 us; speedup 1.0000x reference)
//
#include <hip/hip_runtime.h>
#include <math.h>

typedef _Float16 f16x8 __attribute__((ext_vector_type(8)));
typedef _Float16 f16x2 __attribute__((ext_vector_type(2)));
typedef float f32x4 __attribute__((ext_vector_type(4)));

namespace {
constexpr int B_ = 16, C_ = 128, H_ = 96, W_ = 96;
constexpr int HW_ = H_ * W_;      // 9216
constexpr int G_ = 4, S_ = 2;
constexpr int CO_ = 32;
constexpr int COUT_ = 64;
constexpr int HO_ = 192, WO_ = 192;
constexpr int HWO_ = HO_ * WO_;   // 36864
constexpr int CPG_ = C_ / G_;     // 32
constexpr int TH_ = 8, TW_ = 32;
constexpr int HALO_H = TH_ + 2, HALO_W = TW_ + 2;
constexpr int NPOS = HALO_H * HALO_W;   // 340
constexpr int NITEM = NPOS * 4;         // 1360
constexpr int TILES = (WO_ / TW_) * (HO_ / TH_);  // 144
constexpr int BPI = HW_ / 256;    // 36 blocks/image for 96x96 MFMA kernels
constexpr int XPB = HW_ / 64;     // 144 transpose blocks/image

// ws float offsets (f16[N] = N/2 floats)
constexpr size_t WS_XT     = 0;                    // f16[18874368] = 9437184 f
constexpr size_t WS_OFF1T  = 9437184;              // f16[4718592]  = 2359296 f
constexpr size_t WS_COORDS = 11796480;             // f32[4718592]
constexpr size_t WS_WPWH   = 16515072;             // f16[8192] = 4096 f
constexpr size_t WS_WO1H   = 16519168;             // f16[4096] = 2048 f
constexpr size_t WS_WO2H   = 16521216;             // f16[9216] = 4608 f
constexpr size_t WS_WDWSH  = 16525824;             // f16[1152] = 576 f
constexpr size_t WS_BIAS2H = 16526400;             // f16[128]  = 64 f
constexpr size_t WS_Y      = 16526464;
constexpr size_t IMG_YF16  = (size_t)G_ * 4 * HWO_ * 8;   // 4718592 f16 / image
constexpr int PIPE_P = 4;                                  // images per pipe chunk
// two P-image y buffers (in float units: f16/2)
constexpr size_t NEED_PIPE = (WS_Y + 2 * PIPE_P * IMG_YF16 / 2) * 4;  // ~141.6 MB

constexpr int PREP_N = 8192 + 4096 + 9216 + 1152 + 128;   // 22784
}

__device__ __forceinline__ f16x8 splat8(_Float16 s) {
  return (f16x8){s, s, s, s, s, s, s, s};
}

// --- Kernel P: fp16 casts (Wpw, Wo1, Wo2 k-reordered, BN-folded dw+bias) ---
__global__ __launch_bounds__(256) void k_prep(
    const float* __restrict__ Wpw, const float* __restrict__ Wo1,
    const float* __restrict__ Wo2, const float* __restrict__ Wdw,
    const float* __restrict__ bn_gamma, const float* __restrict__ bn_beta,
    const float* __restrict__ bn_mean, const float* __restrict__ bn_var,
    _Float16* __restrict__ wpwH, _Float16* __restrict__ wo1H,
    _Float16* __restrict__ wo2H, _Float16* __restrict__ wdwSh,
    _Float16* __restrict__ bias2h) {
  int i = blockIdx.x * 256 + threadIdx.x;
  if (i < 8192) {
    wpwH[i] = (_Float16)Wpw[i];
  } else if (i < 8192 + 4096) {
    int j = i - 8192;
    wo1H[j] = (_Float16)Wo1[j];                 // keep [o][c]
  } else if (i < 8192 + 4096 + 9216) {
    int j = i - 8192 - 4096;                    // dst [o][tap*32+ci]
    int o = j / 288, r = j % 288;
    int tap = r / 32, ci = r % 32;
    wo2H[j] = (_Float16)Wo2[o * 288 + ci * 9 + tap];
  } else if (i < 8192 + 4096 + 9216 + 1152) {
    int j = i - 8192 - 4096 - 9216;             // Wdw is [c][9]
    int c = j / 9, t = j % 9;
    float sc = bn_gamma[c] * rsqrtf(bn_var[c] + 1e-5f);
    wdwSh[t * C_ + c] = (_Float16)(Wdw[j] * sc);
  } else if (i < PREP_N) {
    int c = i - (8192 + 4096 + 9216 + 1152);
    float sc = bn_gamma[c] * rsqrtf(bn_var[c] + 1e-5f);
    bias2h[c] = (_Float16)(bn_beta[c] - bn_mean[c] * sc);
  }
}

// --- Kernel X: transpose x [b][c][px] f32 -> xT [b][px][c] f16 ---
__global__ __launch_bounds__(256, 4) void k_xpose(const float* __restrict__ x,
                                                  _Float16* __restrict__ xT) {
  __shared__ float t[64][130];
  int bid = blockIdx.x;                       // B*XPB = 2304, %8==0
  int swz = (bid & 7) * (B_ * XPB / 8) + (bid >> 3);
  int b = swz / XPB, px0 = (swz % XPB) * 64;
  int tid = threadIdx.x;
  int lane = tid & 63, wv = tid >> 6;
  const float* xb = x + (size_t)b * C_ * HW_ + px0 + lane;
  for (int c = wv; c < C_; c += 4) t[lane][c] = xb[(size_t)c * HW_];
  __syncthreads();
  _Float16* ob = xT + ((size_t)b * HW_ + px0) * C_;
#pragma unroll
  for (int k = 0; k < 4; ++k) {
    int cid = tid + 256 * k;
    int px = cid >> 4, part = cid & 15;
    f16x8 v;
#pragma unroll
    for (int j = 0; j < 8; ++j) v[j] = (_Float16)t[px][part * 8 + j];
    *(f16x8*)&ob[(size_t)px * C_ + part * 8] = v;
  }
}

// --- Kernel A (MFMA): 1x1 conv 128->32 + bias -> off1t[b][px][32] fp16 ---
__global__ __launch_bounds__(256, 4) void k_off1m(
    const _Float16* __restrict__ xT, const _Float16* __restrict__ wo1H,
    const float* __restrict__ bo1, _Float16* __restrict__ off1t) {
  __shared__ float clds[32][257];
  int bid = blockIdx.x;                       // 576, %8==0
  int swz = (bid & 7) * (B_ * BPI / 8) + (bid >> 3);
  int b = swz / BPI, p0 = (swz % BPI) * 256;
  int tid = threadIdx.x;
  int lane = tid & 63, wv_ = tid >> 6;
  int lr = lane & 15, lk = lane >> 4;

  f32x4 acc[4][2];
#pragma unroll
  for (int mt = 0; mt < 4; ++mt)
#pragma unroll
    for (int nt = 0; nt < 2; ++nt) acc[mt][nt] = (f32x4){0.f, 0.f, 0.f, 0.f};

  const _Float16* xb = xT + ((size_t)b * HW_ + p0) * C_;
#pragma unroll
  for (int kk = 0; kk < 4; ++kk) {
    f16x8 afr[4];
#pragma unroll
    for (int mt = 0; mt < 4; ++mt)
      afr[mt] = *(const f16x8*)&xb[(size_t)((wv_ * 4 + mt) * 16 + lr) * C_ +
                                   kk * 32 + lk * 8];
#pragma unroll
    for (int nt = 0; nt < 2; ++nt) {
      f16x8 bfr = *(const f16x8*)&wo1H[(nt * 16 + lr) * C_ + kk * 32 + lk * 8];
#pragma unroll
      for (int mt = 0; mt < 4; ++mt)
        acc[mt][nt] = __builtin_amdgcn_mfma_f32_16x16x32_f16(afr[mt], bfr,
                                                             acc[mt][nt], 0, 0, 0);
    }
  }
#pragma unroll
  for (int nt = 0; nt < 2; ++nt)
#pragma unroll
    for (int mt = 0; mt < 4; ++mt)
#pragma unroll
      for (int r = 0; r < 4; ++r)
        clds[nt * 16 + lr][(wv_ * 4 + mt) * 16 + lk * 4 + r] = acc[mt][nt][r];
  __syncthreads();
  _Float16* orow = off1t + ((size_t)b * HW_ + p0 + tid) * 32;
#pragma unroll
  for (int q = 0; q < 4; ++q) {
    f16x8 v;
#pragma unroll
    for (int j = 0; j < 8; ++j)
      v[j] = (_Float16)(clds[q * 8 + j][tid] + bo1[q * 8 + j]);
    *(f16x8*)&orow[q * 8] = v;   // 64B/thread contiguous
  }
}

// --- Kernel B (MFMA): 3x3 dil(2) conv (K=9 taps x 32) -> sample coords ---
__global__ __launch_bounds__(256, 4) void k_coordsm(
    const _Float16* __restrict__ off1t, const _Float16* __restrict__ wo2H,
    float* __restrict__ coords) {
  __shared__ float clds[32][257];
  int bid = blockIdx.x;
  int swz = (bid & 7) * (B_ * BPI / 8) + (bid >> 3);
  int b = swz / BPI, p0 = (swz % BPI) * 256;
  int tid = threadIdx.x;
  int lane = tid & 63, wv_ = tid >> 6;
  int lr = lane & 15, lk = lane >> 4;

  f32x4 acc[4][2];
#pragma unroll
  for (int mt = 0; mt < 4; ++mt)
#pragma unroll
    for (int nt = 0; nt < 2; ++nt) acc[mt][nt] = (f32x4){0.f, 0.f, 0.f, 0.f};

  const _Float16* ob = off1t + (size_t)b * HW_ * 32;
  int hh[4], ww[4];
#pragma unroll
  for (int mt = 0; mt < 4; ++mt) {
    int px = p0 + (wv_ * 4 + mt) * 16 + lr;
    hh[mt] = px / W_;
    ww[mt] = px % W_;
  }
#pragma unroll
  for (int tap = 0; tap < 9; ++tap) {
    int dy2 = (tap / 3 - 1) * 2, dx2 = (tap % 3 - 1) * 2;
    f16x8 afr[4];
#pragma unroll
    for (int mt = 0; mt < 4; ++mt) {
      int h2 = hh[mt] + dy2, w2 = ww[mt] + dx2;
      f16x8 a = {};
      if ((unsigned)h2 < (unsigned)H_ && (unsigned)w2 < (unsigned)W_)
        a = *(const f16x8*)&ob[(size_t)(h2 * W_ + w2) * 32 + lk * 8];
      afr[mt] = a;
    }
#pragma unroll
    for (int nt = 0; nt < 2; ++nt) {
      f16x8 bfr = *(const f16x8*)&wo2H[(nt * 16 + lr) * 288 + tap * 32 + lk * 8];
#pragma unroll
      for (int mt = 0; mt < 4; ++mt)
        acc[mt][nt] = __builtin_amdgcn_mfma_f32_16x16x32_f16(afr[mt], bfr,
                                                             acc[mt][nt], 0, 0, 0);
    }
  }
#pragma unroll
  for (int nt = 0; nt < 2; ++nt)
#pragma unroll
    for (int mt = 0; mt < 4; ++mt)
#pragma unroll
      for (int r = 0; r < 4; ++r)
        clds[nt * 16 + lr][(wv_ * 4 + mt) * 16 + lk * 4 + r] = acc[mt][nt][r];
  __syncthreads();

  int px = p0 + tid;
  int h = px / W_, w = px % W_;
  float cwv = (float)w + sinf((float)M_PI * (float)(w + 1) / (float)W_);
  float chv = (float)h + sinf((float)M_PI * (float)(h + 1) / (float)H_);
  float* cb = coords + (size_t)b * G_ * HWO_ * 2;
#pragma unroll
  for (int g = 0; g < G_; ++g) {
#pragma unroll
    for (int sh = 0; sh < S_; ++sh) {
#pragma unroll
      for (int sw = 0; sw < S_; ++sw) {
        int idx = g * 4 + sh * 2 + sw;
        float offx = clds[idx][tid] * 0.25f + (sw ? 0.25f : -0.25f);
        float offy = clds[16 + idx][tid] * 0.25f + (sh ? 0.25f : -0.25f);
        float ix = fminf(fmaxf(cwv + offx - 0.5f, 0.f), (float)(W_ - 1));
        float iy = fminf(fmaxf(chv + offy - 0.5f, 0.f), (float)(H_ - 1));
        float2* dst = (float2*)(cb + (((size_t)g * HO_ + 2 * h + sh) * WO_
                                      + 2 * w + sw) * 2);
        *dst = (float2){ix, iy};
      }
    }
  }
}

// --- Kernel SG: block-specialized sample ∥ gemm (software pipeline) ---
// Blocks [0, snimg*TILES): grid_sample+dw (R17 k_sample body) for chunk sb0,
// writing ys. Remaining blocks: streaming GEMM (R17 k_gemm body) for chunk
// gb0, reading yg (written by a PREVIOUS launch — stream order guarantees
// visibility; no intra-launch dependency). VALU-bound half hides BW-bound half.
__global__ __launch_bounds__(256, 6) void k_sg(
    const _Float16* __restrict__ xT, const float* __restrict__ coords,
    const _Float16* __restrict__ wdwSh, const _Float16* __restrict__ bias2h,
    const _Float16* __restrict__ wpwH, const float* __restrict__ bpw,
    float* __restrict__ out, _Float16* __restrict__ ys,
    const _Float16* __restrict__ yg, int sb0, int snimg, int gb0, int gnimg) {
  __shared__ __align__(16) unsigned char pool[23424];  // up4 | clds16 overlay
  int nsb = snimg * TILES;
  int bid = blockIdx.x;
  int tid = threadIdx.x;
  int lane = tid & 63, wv_ = tid >> 6;
  int lr = lane & 15, lk = lane >> 4;

  if (bid < nsb) {
    // ================= sample half =================
    _Float16* up4 = (_Float16*)pool;
    int swz = (bid & 7) * (nsb >> 3) + (bid >> 3);   // nsb % 8 == 0
    int bl = swz / TILES;
    int b = sb0 + bl;
    int t = swz % TILES;
    int oh0 = (t / (WO_ / TW_)) * TH_;
    int ow0 = (t % (WO_ / TW_)) * TW_;
    int py = tid >> 5, px = tid & 31;
    int p_out = (oh0 + py) * WO_ + ow0 + px;

    const _Float16* xbase = xT + (size_t)b * HW_ * C_;
    _Float16* ydst = ys + (size_t)bl * IMG_YF16;
    for (int g = 0; g < G_; ++g) {
      __syncthreads();  // protects up4 reuse across g
      const float* cbase = coords + (((size_t)b * G_ + g) * HWO_) * 2;
      const _Float16* xg = xbase + g * CPG_;
#pragma unroll
      for (int r = 0; r < 6; ++r) {
        int wi = tid + r * 256;
        if (r == 5 && wi >= NITEM) continue;  // exec-mask guard, last round
        int p = wi >> 2, cq = wi & 3;
        int hy = oh0 + p / HALO_W - 1;
        int hx = ow0 + p % HALO_W - 1;
        f16x8 v = {};
        if (hy >= 0 && hy < HO_ && hx >= 0 && hx < WO_) {
          float2 c2 = *(const float2*)&cbase[((size_t)hy * WO_ + hx) * 2];
          float ix = c2.x, iy = c2.y;
          float x0f = floorf(ix), y0f = floorf(iy);
          float wx = ix - x0f, wy = iy - y0f;
          int x0 = (int)x0f, y0 = (int)y0f;  // already in [0, 95]
          int x1 = min(x0 + 1, W_ - 1);
          int y1 = min(y0 + 1, H_ - 1);
          f16x8 h00 = splat8((_Float16)((1.f - wx) * (1.f - wy)));
          f16x8 h01 = splat8((_Float16)(wx * (1.f - wy)));
          f16x8 h10 = splat8((_Float16)((1.f - wx) * wy));
          f16x8 h11 = splat8((_Float16)(wx * wy));
          const _Float16* xc = xg + cq * 8;
          f16x8 a00 = *(const f16x8*)&xc[(size_t)(y0 * W_ + x0) * C_];
          f16x8 a01 = *(const f16x8*)&xc[(size_t)(y0 * W_ + x1) * C_];
          f16x8 a10 = *(const f16x8*)&xc[(size_t)(y1 * W_ + x0) * C_];
          f16x8 a11 = *(const f16x8*)&xc[(size_t)(y1 * W_ + x1) * C_];
          v = a00 * h00 + a01 * h01 + a10 * h10 + a11 * h11;  // v_pk_fma_f16
        }
        *(f16x8*)&up4[((size_t)cq * NPOS + p) * 8] = v;  // aligned b128 store
      }
      __syncthreads();

      // dw3x3+BN+ReLU: packed fp16 accumulation
#pragma unroll
      for (int q = 0; q < 4; ++q) {
        f16x8 acc = *(const f16x8*)&bias2h[g * CPG_ + q * 8];  // uniform s_load
#pragma unroll
        for (int tt = 0; tt < 9; ++tt) {
          int dy = tt / 3, dx = tt % 3;
          f16x8 pk = *(const f16x8*)
              &up4[((size_t)q * NPOS + (py + dy) * HALO_W + px + dx) * 8];
          f16x8 wv = *(const f16x8*)&wdwSh[tt * C_ + g * CPG_ + q * 8];
          acc += pk * wv;   // 4x v_pk_fma_f16
        }
        f16x8 yv;
#pragma unroll
        for (int j = 0; j < 8; ++j)
          yv[j] = acc[j] > (_Float16)0.f ? acc[j] : (_Float16)0.f;
        *(f16x8*)&ydst[(((size_t)g * 4 + q) * HWO_ + p_out) * 8] = yv;
      }
    }
  } else {
    // ================= gemm half =================
    float (*clds16)[257] = (float(*)[257])pool;  // 16448 B <= 23424 B
    int gbid = bid - nsb;
    int ngb = gnimg * TILES;
    int swz = (gbid & 7) * (ngb >> 3) + (gbid >> 3);  // ngb % 8 == 0
    int bl = swz / TILES;
    int b = gb0 + bl;
    int p0 = (swz % TILES) * 256;

    f32x4 acc[4][4];
#pragma unroll
    for (int mt = 0; mt < 4; ++mt)
#pragma unroll
      for (int nt = 0; nt < 4; ++nt) acc[mt][nt] = (f32x4){0.f, 0.f, 0.f, 0.f};

    const _Float16* ybl = yg + (size_t)bl * IMG_YF16;
#pragma unroll
    for (int kk = 0; kk < 4; ++kk) {
      f16x8 afr[4];
#pragma unroll
      for (int mt = 0; mt < 4; ++mt)
        afr[mt] = *(const f16x8*)&ybl[(((size_t)(kk * 4 + lk) * HWO_) + p0 +
                                       (wv_ * 4 + mt) * 16 + lr) * 8];
#pragma unroll
      for (int nt = 0; nt < 4; ++nt) {
        f16x8 bfr = *(const f16x8*)&wpwH[(nt * 16 + lr) * C_ + kk * CPG_ + lk * 8];
#pragma unroll
        for (int mt = 0; mt < 4; ++mt)
          acc[mt][nt] = __builtin_amdgcn_mfma_f32_16x16x32_f16(afr[mt], bfr,
                                                               acc[mt][nt], 0, 0, 0);
      }
    }
#pragma unroll
    for (int hq = 0; hq < 4; ++hq) {
      if (hq) __syncthreads();
#pragma unroll
      for (int mt = 0; mt < 4; ++mt) {
#pragma unroll
        for (int r = 0; r < 4; ++r)
          clds16[lr][(wv_ * 4 + mt) * 16 + lk * 4 + r] = acc[mt][hq][r];
      }
      __syncthreads();
#pragma unroll
      for (int i = 0; i < 16; ++i) {
        int o = hq * 16 + i;
        out[((size_t)b * COUT_ + o) * HWO_ + p0 + tid] = clds16[i][tid] + bpw[o];
      }
    }
  }
}

extern "C" void kernel_launch(void* const* d_in, const int* in_sizes, int n_in,
                              void* d_out, int out_size, void* d_ws, size_t ws_size,
                              hipStream_t stream) {
  const float* x        = (const float*)d_in[0];
  const float* Wo1      = (const float*)d_in[1];
  const float* bo1      = (const float*)d_in[2];
  const float* Wo2      = (const float*)d_in[3];
  const float* Wdw      = (const float*)d_in[4];
  const float* bn_gamma = (const float*)d_in[5];
  const float* bn_beta  = (const float*)d_in[6];
  const float* bn_mean  = (const float*)d_in[7];
  const float* bn_var   = (const float*)d_in[8];
  const float* Wpw      = (const float*)d_in[9];
  const float* bpw      = (const float*)d_in[10];
  float* out = (float*)d_out;

  float* ws = (float*)d_ws;
  _Float16* xT     = (_Float16*)(ws + WS_XT);
  _Float16* off1t  = (_Float16*)(ws + WS_OFF1T);
  float* coords    = ws + WS_COORDS;
  _Float16* wpwH   = (_Float16*)(ws + WS_WPWH);
  _Float16* wo1H   = (_Float16*)(ws + WS_WO1H);
  _Float16* wo2H   = (_Float16*)(ws + WS_WO2H);
  _Float16* wdwSh  = (_Float16*)(ws + WS_WDWSH);
  _Float16* bias2h = (_Float16*)(ws + WS_BIAS2H);

  k_prep   <<<(PREP_N + 255) / 256, 256, 0, stream>>>(
      Wpw, Wo1, Wo2, Wdw, bn_gamma, bn_beta, bn_mean, bn_var,
      wpwH, wo1H, wo2H, wdwSh, bias2h);
  k_xpose  <<<B_ * XPB, 256, 0, stream>>>(x, xT);
  k_off1m  <<<B_ * BPI, 256, 0, stream>>>(xT, wo1H, bo1, off1t);
  k_coordsm<<<B_ * BPI, 256, 0, stream>>>(off1t, wo2H, coords);

  if (ws_size >= NEED_PIPE) {
    // software pipeline, P=4 images per chunk, double-buffered y
    constexpr int P = PIPE_P;
    _Float16* y0 = (_Float16*)(ws + WS_Y);
    _Float16* y1 = y0 + (size_t)P * IMG_YF16;
    // S(0-3)
    k_sg<<<P * TILES, 256, 0, stream>>>(xT, coords, wdwSh, bias2h, wpwH, bpw,
                                        out, y0, y0, 0, P, 0, 0);
    // S(4-7) || G(0-3)
    k_sg<<<2 * P * TILES, 256, 0, stream>>>(xT, coords, wdwSh, bias2h, wpwH,
                                            bpw, out, y1, y0, P, P, 0, P);
    // S(8-11) || G(4-7)
    k_sg<<<2 * P * TILES, 256, 0, stream>>>(xT, coords, wdwSh, bias2h, wpwH,
                                            bpw, out, y0, y1, 2 * P, P, P, P);
    // S(12-15) || G(8-11)
    k_sg<<<2 * P * TILES, 256, 0, stream>>>(xT, coords, wdwSh, bias2h, wpwH,
                                            bpw, out, y1, y0, 3 * P, P, 2 * P, P);
    // G(12-15)
    k_sg<<<P * TILES, 256, 0, stream>>>(xT, coords, wdwSh, bias2h, wpwH, bpw,
                                        out, y1, y1, 0, 0, 3 * P, P);
  } else {
    // serial fallback: 1 image at a time, y aliases off1t (dead after coordsm)
    _Float16* ya = (_Float16*)(ws + WS_OFF1T);
    for (int i = 0; i < B_; ++i) {
      k_sg<<<TILES, 256, 0, stream>>>(xT, coords, wdwSh, bias2h, wpwH, bpw,
                                      out, ya, ya, i, 1, 0, 0);
      k_sg<<<TILES, 256, 0, stream>>>(xT, coords, wdwSh, bias2h, wpwH, bpw,
                                      out, ya, ya, 0, 0, i, 1);
    }
  }
}

// Round 19
// 199.851 us; speedup vs baseline: 1.5805x; 1.5805x over previous
//
#include <hip/hip_runtime.h>
#include <math.h>

typedef _Float16 f16x8 __attribute__((ext_vector_type(8)));
typedef _Float16 f16x2 __attribute__((ext_vector_type(2)));
typedef float f32x4 __attribute__((ext_vector_type(4)));

namespace {
constexpr int B_ = 16, C_ = 128, H_ = 96, W_ = 96;
constexpr int HW_ = H_ * W_;      // 9216
constexpr int G_ = 4, S_ = 2;
constexpr int CO_ = 32;
constexpr int COUT_ = 64;
constexpr int HO_ = 192, WO_ = 192;
constexpr int HWO_ = HO_ * WO_;   // 36864
constexpr int CPG_ = C_ / G_;     // 32
constexpr int TH_ = 8, TW_ = 32;
constexpr int HALO_H = TH_ + 2, HALO_W = TW_ + 2;
constexpr int NPOS = HALO_H * HALO_W;   // 340
constexpr int NITEM = NPOS * 4;         // 1360
constexpr int TILES = (WO_ / TW_) * (HO_ / TH_);  // 144
constexpr int BPI = HW_ / 256;    // 36 blocks/image for 96x96 MFMA kernels
constexpr int XPB = HW_ / 64;     // 144 transpose blocks/image

// ws float offsets (f16[N] = N/2 floats)
constexpr size_t WS_XT     = 0;                    // f16[18874368] = 9437184 f
constexpr size_t WS_OFF1T  = 9437184;              // f16[4718592]  = 2359296 f
constexpr size_t WS_COORDS = 11796480;             // f32[4718592]
constexpr size_t WS_WPWH   = 16515072;             // f16[8192] = 4096 f
constexpr size_t WS_WO1H   = 16519168;             // f16[4096] = 2048 f
constexpr size_t WS_WO2H   = 16521216;             // f16[9216] = 4608 f
constexpr size_t WS_WDWSH  = 16525824;             // f16[1152] = 576 f
constexpr size_t WS_BIAS2H = 16526400;             // f16[128]  = 64 f
constexpr size_t WS_Y      = 16526464;
constexpr size_t IMG_YF16  = (size_t)G_ * 4 * HWO_ * 8;   // 4718592 f16 / image
constexpr int PIPE_P = 4;                                  // images per pipe chunk
constexpr size_t NEED_PIPE = (WS_Y + 2 * PIPE_P * IMG_YF16 / 2) * 4;  // ~141.6 MB

constexpr int PREP_N = 8192 + 4096 + 9216 + 1152 + 128;   // 22784
}

__device__ __forceinline__ f16x8 splat8(_Float16 s) {
  return (f16x8){s, s, s, s, s, s, s, s};
}

// --- Kernel P: fp16 casts (Wpw, Wo1, Wo2 k-reordered, BN-folded dw+bias) ---
__global__ __launch_bounds__(256) void k_prep(
    const float* __restrict__ Wpw, const float* __restrict__ Wo1,
    const float* __restrict__ Wo2, const float* __restrict__ Wdw,
    const float* __restrict__ bn_gamma, const float* __restrict__ bn_beta,
    const float* __restrict__ bn_mean, const float* __restrict__ bn_var,
    _Float16* __restrict__ wpwH, _Float16* __restrict__ wo1H,
    _Float16* __restrict__ wo2H, _Float16* __restrict__ wdwSh,
    _Float16* __restrict__ bias2h) {
  int i = blockIdx.x * 256 + threadIdx.x;
  if (i < 8192) {
    wpwH[i] = (_Float16)Wpw[i];
  } else if (i < 8192 + 4096) {
    int j = i - 8192;
    wo1H[j] = (_Float16)Wo1[j];                 // keep [o][c]
  } else if (i < 8192 + 4096 + 9216) {
    int j = i - 8192 - 4096;                    // dst [o][tap*32+ci]
    int o = j / 288, r = j % 288;
    int tap = r / 32, ci = r % 32;
    wo2H[j] = (_Float16)Wo2[o * 288 + ci * 9 + tap];
  } else if (i < 8192 + 4096 + 9216 + 1152) {
    int j = i - 8192 - 4096 - 9216;             // Wdw is [c][9]
    int c = j / 9, t = j % 9;
    float sc = bn_gamma[c] * rsqrtf(bn_var[c] + 1e-5f);
    wdwSh[t * C_ + c] = (_Float16)(Wdw[j] * sc);
  } else if (i < PREP_N) {
    int c = i - (8192 + 4096 + 9216 + 1152);
    float sc = bn_gamma[c] * rsqrtf(bn_var[c] + 1e-5f);
    bias2h[c] = (_Float16)(bn_beta[c] - bn_mean[c] * sc);
  }
}

// --- Kernel X: transpose x [b][c][px] f32 -> xT [b][px][c] f16 ---
__global__ __launch_bounds__(256, 4) void k_xpose(const float* __restrict__ x,
                                                  _Float16* __restrict__ xT) {
  __shared__ float t[64][130];
  int bid = blockIdx.x;                       // B*XPB = 2304, %8==0
  int swz = (bid & 7) * (B_ * XPB / 8) + (bid >> 3);
  int b = swz / XPB, px0 = (swz % XPB) * 64;
  int tid = threadIdx.x;
  int lane = tid & 63, wv = tid >> 6;
  const float* xb = x + (size_t)b * C_ * HW_ + px0 + lane;
  for (int c = wv; c < C_; c += 4) t[lane][c] = xb[(size_t)c * HW_];
  __syncthreads();
  _Float16* ob = xT + ((size_t)b * HW_ + px0) * C_;
#pragma unroll
  for (int k = 0; k < 4; ++k) {
    int cid = tid + 256 * k;
    int px = cid >> 4, part = cid & 15;
    f16x8 v;
#pragma unroll
    for (int j = 0; j < 8; ++j) v[j] = (_Float16)t[px][part * 8 + j];
    *(f16x8*)&ob[(size_t)px * C_ + part * 8] = v;
  }
}

// --- Kernel A (MFMA): 1x1 conv 128->32 + bias -> off1t[b][px][32] fp16 ---
__global__ __launch_bounds__(256, 4) void k_off1m(
    const _Float16* __restrict__ xT, const _Float16* __restrict__ wo1H,
    const float* __restrict__ bo1, _Float16* __restrict__ off1t) {
  __shared__ float clds[32][257];
  int bid = blockIdx.x;                       // 576, %8==0
  int swz = (bid & 7) * (B_ * BPI / 8) + (bid >> 3);
  int b = swz / BPI, p0 = (swz % BPI) * 256;
  int tid = threadIdx.x;
  int lane = tid & 63, wv_ = tid >> 6;
  int lr = lane & 15, lk = lane >> 4;

  f32x4 acc[4][2];
#pragma unroll
  for (int mt = 0; mt < 4; ++mt)
#pragma unroll
    for (int nt = 0; nt < 2; ++nt) acc[mt][nt] = (f32x4){0.f, 0.f, 0.f, 0.f};

  const _Float16* xb = xT + ((size_t)b * HW_ + p0) * C_;
#pragma unroll
  for (int kk = 0; kk < 4; ++kk) {
    f16x8 afr[4];
#pragma unroll
    for (int mt = 0; mt < 4; ++mt)
      afr[mt] = *(const f16x8*)&xb[(size_t)((wv_ * 4 + mt) * 16 + lr) * C_ +
                                   kk * 32 + lk * 8];
#pragma unroll
    for (int nt = 0; nt < 2; ++nt) {
      f16x8 bfr = *(const f16x8*)&wo1H[(nt * 16 + lr) * C_ + kk * 32 + lk * 8];
#pragma unroll
      for (int mt = 0; mt < 4; ++mt)
        acc[mt][nt] = __builtin_amdgcn_mfma_f32_16x16x32_f16(afr[mt], bfr,
                                                             acc[mt][nt], 0, 0, 0);
    }
  }
#pragma unroll
  for (int nt = 0; nt < 2; ++nt)
#pragma unroll
    for (int mt = 0; mt < 4; ++mt)
#pragma unroll
      for (int r = 0; r < 4; ++r)
        clds[nt * 16 + lr][(wv_ * 4 + mt) * 16 + lk * 4 + r] = acc[mt][nt][r];
  __syncthreads();
  _Float16* orow = off1t + ((size_t)b * HW_ + p0 + tid) * 32;
#pragma unroll
  for (int q = 0; q < 4; ++q) {
    f16x8 v;
#pragma unroll
    for (int j = 0; j < 8; ++j)
      v[j] = (_Float16)(clds[q * 8 + j][tid] + bo1[q * 8 + j]);
    *(f16x8*)&orow[q * 8] = v;   // 64B/thread contiguous
  }
}

// --- Kernel B (MFMA): 3x3 dil(2) conv (K=9 taps x 32) -> sample coords ---
__global__ __launch_bounds__(256, 4) void k_coordsm(
    const _Float16* __restrict__ off1t, const _Float16* __restrict__ wo2H,
    float* __restrict__ coords) {
  __shared__ float clds[32][257];
  int bid = blockIdx.x;
  int swz = (bid & 7) * (B_ * BPI / 8) + (bid >> 3);
  int b = swz / BPI, p0 = (swz % BPI) * 256;
  int tid = threadIdx.x;
  int lane = tid & 63, wv_ = tid >> 6;
  int lr = lane & 15, lk = lane >> 4;

  f32x4 acc[4][2];
#pragma unroll
  for (int mt = 0; mt < 4; ++mt)
#pragma unroll
    for (int nt = 0; nt < 2; ++nt) acc[mt][nt] = (f32x4){0.f, 0.f, 0.f, 0.f};

  const _Float16* ob = off1t + (size_t)b * HW_ * 32;
  int hh[4], ww[4];
#pragma unroll
  for (int mt = 0; mt < 4; ++mt) {
    int px = p0 + (wv_ * 4 + mt) * 16 + lr;
    hh[mt] = px / W_;
    ww[mt] = px % W_;
  }
#pragma unroll
  for (int tap = 0; tap < 9; ++tap) {
    int dy2 = (tap / 3 - 1) * 2, dx2 = (tap % 3 - 1) * 2;
    f16x8 afr[4];
#pragma unroll
    for (int mt = 0; mt < 4; ++mt) {
      int h2 = hh[mt] + dy2, w2 = ww[mt] + dx2;
      f16x8 a = {};
      if ((unsigned)h2 < (unsigned)H_ && (unsigned)w2 < (unsigned)W_)
        a = *(const f16x8*)&ob[(size_t)(h2 * W_ + w2) * 32 + lk * 8];
      afr[mt] = a;
    }
#pragma unroll
    for (int nt = 0; nt < 2; ++nt) {
      f16x8 bfr = *(const f16x8*)&wo2H[(nt * 16 + lr) * 288 + tap * 32 + lk * 8];
#pragma unroll
      for (int mt = 0; mt < 4; ++mt)
        acc[mt][nt] = __builtin_amdgcn_mfma_f32_16x16x32_f16(afr[mt], bfr,
                                                             acc[mt][nt], 0, 0, 0);
    }
  }
#pragma unroll
  for (int nt = 0; nt < 2; ++nt)
#pragma unroll
    for (int mt = 0; mt < 4; ++mt)
#pragma unroll
      for (int r = 0; r < 4; ++r)
        clds[nt * 16 + lr][(wv_ * 4 + mt) * 16 + lk * 4 + r] = acc[mt][nt][r];
  __syncthreads();

  int px = p0 + tid;
  int h = px / W_, w = px % W_;
  float cwv = (float)w + sinf((float)M_PI * (float)(w + 1) / (float)W_);
  float chv = (float)h + sinf((float)M_PI * (float)(h + 1) / (float)H_);
  float* cb = coords + (size_t)b * G_ * HWO_ * 2;
#pragma unroll
  for (int g = 0; g < G_; ++g) {
#pragma unroll
    for (int sh = 0; sh < S_; ++sh) {
#pragma unroll
      for (int sw = 0; sw < S_; ++sw) {
        int idx = g * 4 + sh * 2 + sw;
        float offx = clds[idx][tid] * 0.25f + (sw ? 0.25f : -0.25f);
        float offy = clds[16 + idx][tid] * 0.25f + (sh ? 0.25f : -0.25f);
        float ix = fminf(fmaxf(cwv + offx - 0.5f, 0.f), (float)(W_ - 1));
        float iy = fminf(fmaxf(chv + offy - 0.5f, 0.f), (float)(H_ - 1));
        float2* dst = (float2*)(cb + (((size_t)g * HO_ + 2 * h + sh) * WO_
                                      + 2 * w + sw) * 2);
        *dst = (float2){ix, iy};
      }
    }
  }
}

// --- Kernel SG: block-specialized sample ∥ gemm (software pipeline) ---
// bounds (256,4): R18's (256,6) clamped VGPR to 85 -> gemm acc spilled to
// scratch -> runtime throttled residency (0.17% occupancy). At 4 waves/EU the
// allocator gets 128 VGPRs: no spill; residency ~5 blocks/CU (VGPR-limited).
__global__ __launch_bounds__(256, 4) void k_sg(
    const _Float16* __restrict__ xT, const float* __restrict__ coords,
    const _Float16* __restrict__ wdwSh, const _Float16* __restrict__ bias2h,
    const _Float16* __restrict__ wpwH, const float* __restrict__ bpw,
    float* __restrict__ out, _Float16* __restrict__ ys,
    const _Float16* __restrict__ yg, int sb0, int snimg, int gb0, int gnimg) {
  __shared__ __align__(16) unsigned char pool[23424];  // up4 | clds16 overlay
  int nsb = snimg * TILES;
  int bid = blockIdx.x;
  int tid = threadIdx.x;
  int lane = tid & 63, wv_ = tid >> 6;
  int lr = lane & 15, lk = lane >> 4;

  if (bid < nsb) {
    // ================= sample half =================
    _Float16* up4 = (_Float16*)pool;
    int swz = (bid & 7) * (nsb >> 3) + (bid >> 3);   // nsb % 8 == 0
    int bl = swz / TILES;
    int b = sb0 + bl;
    int t = swz % TILES;
    int oh0 = (t / (WO_ / TW_)) * TH_;
    int ow0 = (t % (WO_ / TW_)) * TW_;
    int py = tid >> 5, px = tid & 31;
    int p_out = (oh0 + py) * WO_ + ow0 + px;

    const _Float16* xbase = xT + (size_t)b * HW_ * C_;
    _Float16* ydst = ys + (size_t)bl * IMG_YF16;
    for (int g = 0; g < G_; ++g) {
      __syncthreads();  // protects up4 reuse across g
      const float* cbase = coords + (((size_t)b * G_ + g) * HWO_) * 2;
      const _Float16* xg = xbase + g * CPG_;
#pragma unroll
      for (int r = 0; r < 6; ++r) {
        int wi = tid + r * 256;
        if (r == 5 && wi >= NITEM) continue;  // exec-mask guard, last round
        int p = wi >> 2, cq = wi & 3;
        int hy = oh0 + p / HALO_W - 1;
        int hx = ow0 + p % HALO_W - 1;
        f16x8 v = {};
        if (hy >= 0 && hy < HO_ && hx >= 0 && hx < WO_) {
          float2 c2 = *(const float2*)&cbase[((size_t)hy * WO_ + hx) * 2];
          float ix = c2.x, iy = c2.y;
          float x0f = floorf(ix), y0f = floorf(iy);
          float wx = ix - x0f, wy = iy - y0f;
          int x0 = (int)x0f, y0 = (int)y0f;  // already in [0, 95]
          int x1 = min(x0 + 1, W_ - 1);
          int y1 = min(y0 + 1, H_ - 1);
          f16x8 h00 = splat8((_Float16)((1.f - wx) * (1.f - wy)));
          f16x8 h01 = splat8((_Float16)(wx * (1.f - wy)));
          f16x8 h10 = splat8((_Float16)((1.f - wx) * wy));
          f16x8 h11 = splat8((_Float16)(wx * wy));
          const _Float16* xc = xg + cq * 8;
          f16x8 a00 = *(const f16x8*)&xc[(size_t)(y0 * W_ + x0) * C_];
          f16x8 a01 = *(const f16x8*)&xc[(size_t)(y0 * W_ + x1) * C_];
          f16x8 a10 = *(const f16x8*)&xc[(size_t)(y1 * W_ + x0) * C_];
          f16x8 a11 = *(const f16x8*)&xc[(size_t)(y1 * W_ + x1) * C_];
          v = a00 * h00 + a01 * h01 + a10 * h10 + a11 * h11;  // v_pk_fma_f16
        }
        *(f16x8*)&up4[((size_t)cq * NPOS + p) * 8] = v;  // aligned b128 store
      }
      __syncthreads();

      // dw3x3+BN+ReLU: packed fp16 accumulation
#pragma unroll
      for (int q = 0; q < 4; ++q) {
        f16x8 acc = *(const f16x8*)&bias2h[g * CPG_ + q * 8];  // uniform s_load
#pragma unroll
        for (int tt = 0; tt < 9; ++tt) {
          int dy = tt / 3, dx = tt % 3;
          f16x8 pk = *(const f16x8*)
              &up4[((size_t)q * NPOS + (py + dy) * HALO_W + px + dx) * 8];
          f16x8 wv = *(const f16x8*)&wdwSh[tt * C_ + g * CPG_ + q * 8];
          acc += pk * wv;   // 4x v_pk_fma_f16
        }
        f16x8 yv;
#pragma unroll
        for (int j = 0; j < 8; ++j)
          yv[j] = acc[j] > (_Float16)0.f ? acc[j] : (_Float16)0.f;
        *(f16x8*)&ydst[(((size_t)g * 4 + q) * HWO_ + p_out) * 8] = yv;
      }
    }
  } else {
    // ================= gemm half =================
    float (*clds16)[257] = (float(*)[257])pool;  // 16448 B <= 23424 B
    int gbid = bid - nsb;
    int ngb = gnimg * TILES;
    int swz = (gbid & 7) * (ngb >> 3) + (gbid >> 3);  // ngb % 8 == 0
    int bl = swz / TILES;
    int b = gb0 + bl;
    int p0 = (swz % TILES) * 256;

    f32x4 acc[4][4];
#pragma unroll
    for (int mt = 0; mt < 4; ++mt)
#pragma unroll
      for (int nt = 0; nt < 4; ++nt) acc[mt][nt] = (f32x4){0.f, 0.f, 0.f, 0.f};

    const _Float16* ybl = yg + (size_t)bl * IMG_YF16;
#pragma unroll
    for (int kk = 0; kk < 4; ++kk) {
      f16x8 afr[4];
#pragma unroll
      for (int mt = 0; mt < 4; ++mt)
        afr[mt] = *(const f16x8*)&ybl[(((size_t)(kk * 4 + lk) * HWO_) + p0 +
                                       (wv_ * 4 + mt) * 16 + lr) * 8];
#pragma unroll
      for (int nt = 0; nt < 4; ++nt) {
        f16x8 bfr = *(const f16x8*)&wpwH[(nt * 16 + lr) * C_ + kk * CPG_ + lk * 8];
#pragma unroll
        for (int mt = 0; mt < 4; ++mt)
          acc[mt][nt] = __builtin_amdgcn_mfma_f32_16x16x32_f16(afr[mt], bfr,
                                                               acc[mt][nt], 0, 0, 0);
      }
    }
#pragma unroll
    for (int hq = 0; hq < 4; ++hq) {
      if (hq) __syncthreads();
#pragma unroll
      for (int mt = 0; mt < 4; ++mt) {
#pragma unroll
        for (int r = 0; r < 4; ++r)
          clds16[lr][(wv_ * 4 + mt) * 16 + lk * 4 + r] = acc[mt][hq][r];
      }
      __syncthreads();
#pragma unroll
      for (int i = 0; i < 16; ++i) {
        int o = hq * 16 + i;
        out[((size_t)b * COUT_ + o) * HWO_ + p0 + tid] = clds16[i][tid] + bpw[o];
      }
    }
  }
}

extern "C" void kernel_launch(void* const* d_in, const int* in_sizes, int n_in,
                              void* d_out, int out_size, void* d_ws, size_t ws_size,
                              hipStream_t stream) {
  const float* x        = (const float*)d_in[0];
  const float* Wo1      = (const float*)d_in[1];
  const float* bo1      = (const float*)d_in[2];
  const float* Wo2      = (const float*)d_in[3];
  const float* Wdw      = (const float*)d_in[4];
  const float* bn_gamma = (const float*)d_in[5];
  const float* bn_beta  = (const float*)d_in[6];
  const float* bn_mean  = (const float*)d_in[7];
  const float* bn_var   = (const float*)d_in[8];
  const float* Wpw      = (const float*)d_in[9];
  const float* bpw      = (const float*)d_in[10];
  float* out = (float*)d_out;

  float* ws = (float*)d_ws;
  _Float16* xT     = (_Float16*)(ws + WS_XT);
  _Float16* off1t  = (_Float16*)(ws + WS_OFF1T);
  float* coords    = ws + WS_COORDS;
  _Float16* wpwH   = (_Float16*)(ws + WS_WPWH);
  _Float16* wo1H   = (_Float16*)(ws + WS_WO1H);
  _Float16* wo2H   = (_Float16*)(ws + WS_WO2H);
  _Float16* wdwSh  = (_Float16*)(ws + WS_WDWSH);
  _Float16* bias2h = (_Float16*)(ws + WS_BIAS2H);

  k_prep   <<<(PREP_N + 255) / 256, 256, 0, stream>>>(
      Wpw, Wo1, Wo2, Wdw, bn_gamma, bn_beta, bn_mean, bn_var,
      wpwH, wo1H, wo2H, wdwSh, bias2h);
  k_xpose  <<<B_ * XPB, 256, 0, stream>>>(x, xT);
  k_off1m  <<<B_ * BPI, 256, 0, stream>>>(xT, wo1H, bo1, off1t);
  k_coordsm<<<B_ * BPI, 256, 0, stream>>>(off1t, wo2H, coords);

  if (ws_size >= NEED_PIPE) {
    // software pipeline, P=4 images per chunk, double-buffered y
    constexpr int P = PIPE_P;
    _Float16* y0 = (_Float16*)(ws + WS_Y);
    _Float16* y1 = y0 + (size_t)P * IMG_YF16;
    // S(0-3)
    k_sg<<<P * TILES, 256, 0, stream>>>(xT, coords, wdwSh, bias2h, wpwH, bpw,
                                        out, y0, y0, 0, P, 0, 0);
    // S(4-7) || G(0-3)
    k_sg<<<2 * P * TILES, 256, 0, stream>>>(xT, coords, wdwSh, bias2h, wpwH,
                                            bpw, out, y1, y0, P, P, 0, P);
    // S(8-11) || G(4-7)
    k_sg<<<2 * P * TILES, 256, 0, stream>>>(xT, coords, wdwSh, bias2h, wpwH,
                                            bpw, out, y0, y1, 2 * P, P, P, P);
    // S(12-15) || G(8-11)
    k_sg<<<2 * P * TILES, 256, 0, stream>>>(xT, coords, wdwSh, bias2h, wpwH,
                                            bpw, out, y1, y0, 3 * P, P, 2 * P, P);
    // G(12-15)
    k_sg<<<P * TILES, 256, 0, stream>>>(xT, coords, wdwSh, bias2h, wpwH, bpw,
                                        out, y1, y1, 0, 0, 3 * P, P);
  } else {
    // serial fallback: 1 image at a time, y aliases off1t (dead after coordsm)
    _Float16* ya = (_Float16*)(ws + WS_OFF1T);
    for (int i = 0; i < B_; ++i) {
      k_sg<<<TILES, 256, 0, stream>>>(xT, coords, wdwSh, bias2h, wpwH, bpw,
                                      out, ya, ya, i, 1, 0, 0);
      k_sg<<<TILES, 256, 0, stream>>>(xT, coords, wdwSh, bias2h, wpwH, bpw,
                                      out, ya, ya, 0, 0, i, 1);
    }
  }
}

// Round 20
// 186.646 us; speedup vs baseline: 1.6923x; 1.0707x over previous
//
#include <hip/hip_runtime.h>
#include <math.h>

typedef _Float16 f16x8 __attribute__((ext_vector_type(8)));
typedef _Float16 f16x2 __attribute__((ext_vector_type(2)));
typedef float f32x4 __attribute__((ext_vector_type(4)));

namespace {
constexpr int B_ = 16, C_ = 128, H_ = 96, W_ = 96;
constexpr int HW_ = H_ * W_;      // 9216
constexpr int G_ = 4, S_ = 2;
constexpr int CO_ = 32;
constexpr int COUT_ = 64;
constexpr int HO_ = 192, WO_ = 192;
constexpr int HWO_ = HO_ * WO_;   // 36864
constexpr int CPG_ = C_ / G_;     // 32
constexpr int TH_ = 8, TW_ = 32;
constexpr int HALO_H = TH_ + 2, HALO_W = TW_ + 2;
constexpr int NPOS = HALO_H * HALO_W;   // 340
constexpr int NITEM = NPOS * 4;         // 1360
constexpr int TILES = (WO_ / TW_) * (HO_ / TH_);  // 144
constexpr int BPI = HW_ / 256;    // 36 blocks/image for 96x96 MFMA kernels
constexpr int XPB = HW_ / 64;     // 144 transpose blocks/image

// ws float offsets (f16[N] = N/2 floats)
constexpr size_t WS_XT     = 0;                    // f16[18874368] = 9437184 f
constexpr size_t WS_OFF1T  = 9437184;              // f16[4718592]  = 2359296 f
constexpr size_t WS_SREC   = 11796480;             // uint2[B*G*HWO] = 4718592 f
constexpr size_t WS_WPWH   = 16515072;             // f16[8192] = 4096 f
constexpr size_t WS_WO1H   = 16519168;             // f16[4096] = 2048 f
constexpr size_t WS_WO2H   = 16521216;             // f16[9216] = 4608 f
constexpr size_t WS_WDWSH  = 16525824;             // f16[1152] = 576 f
constexpr size_t WS_BIAS2H = 16526400;             // f16[128]  = 64 f
constexpr size_t WS_Y      = 16526464;
constexpr size_t IMG_YF16  = (size_t)G_ * 4 * HWO_ * 8;   // 4718592 f16 / image
constexpr size_t Y_FULL_F  = (size_t)B_ * IMG_YF16 / 2;   // 37748736 f
constexpr size_t NEED_FULL = (WS_Y + Y_FULL_F) * 4;       // ~217.1 MB
constexpr size_t NEED_MID  = (WS_Y + Y_FULL_F / 2) * 4;   // ~141.6 MB

constexpr int PREP_N = 8192 + 4096 + 9216 + 1152 + 128;   // 22784
}

__device__ __forceinline__ f16x8 splat8(_Float16 s) {
  return (f16x8){s, s, s, s, s, s, s, s};
}
__device__ __forceinline__ unsigned short h2u(_Float16 h) {
  union { unsigned short u; _Float16 h; } c; c.h = h; return c.u;
}
__device__ __forceinline__ _Float16 u2h(unsigned short u) {
  union { unsigned short u; _Float16 h; } c; c.u = u; return c.h;
}

// --- Kernel P: fp16 casts (Wpw, Wo1, Wo2 k-reordered, BN-folded dw+bias) ---
__global__ __launch_bounds__(256) void k_prep(
    const float* __restrict__ Wpw, const float* __restrict__ Wo1,
    const float* __restrict__ Wo2, const float* __restrict__ Wdw,
    const float* __restrict__ bn_gamma, const float* __restrict__ bn_beta,
    const float* __restrict__ bn_mean, const float* __restrict__ bn_var,
    _Float16* __restrict__ wpwH, _Float16* __restrict__ wo1H,
    _Float16* __restrict__ wo2H, _Float16* __restrict__ wdwSh,
    _Float16* __restrict__ bias2h) {
  int i = blockIdx.x * 256 + threadIdx.x;
  if (i < 8192) {
    wpwH[i] = (_Float16)Wpw[i];
  } else if (i < 8192 + 4096) {
    int j = i - 8192;
    wo1H[j] = (_Float16)Wo1[j];                 // keep [o][c]
  } else if (i < 8192 + 4096 + 9216) {
    int j = i - 8192 - 4096;                    // dst [o][tap*32+ci]
    int o = j / 288, r = j % 288;
    int tap = r / 32, ci = r % 32;
    wo2H[j] = (_Float16)Wo2[o * 288 + ci * 9 + tap];
  } else if (i < 8192 + 4096 + 9216 + 1152) {
    int j = i - 8192 - 4096 - 9216;             // Wdw is [c][9]
    int c = j / 9, t = j % 9;
    float sc = bn_gamma[c] * rsqrtf(bn_var[c] + 1e-5f);
    wdwSh[t * C_ + c] = (_Float16)(Wdw[j] * sc);
  } else if (i < PREP_N) {
    int c = i - (8192 + 4096 + 9216 + 1152);
    float sc = bn_gamma[c] * rsqrtf(bn_var[c] + 1e-5f);
    bias2h[c] = (_Float16)(bn_beta[c] - bn_mean[c] * sc);
  }
}

// --- Kernel X: transpose x [b][c][px] f32 -> xT [b][px][c] f16 ---
__global__ __launch_bounds__(256, 4) void k_xpose(const float* __restrict__ x,
                                                  _Float16* __restrict__ xT) {
  __shared__ float t[64][130];
  int bid = blockIdx.x;                       // B*XPB = 2304, %8==0
  int swz = (bid & 7) * (B_ * XPB / 8) + (bid >> 3);
  int b = swz / XPB, px0 = (swz % XPB) * 64;
  int tid = threadIdx.x;
  int lane = tid & 63, wv = tid >> 6;
  const float* xb = x + (size_t)b * C_ * HW_ + px0 + lane;
  for (int c = wv; c < C_; c += 4) t[lane][c] = xb[(size_t)c * HW_];
  __syncthreads();
  _Float16* ob = xT + ((size_t)b * HW_ + px0) * C_;
#pragma unroll
  for (int k = 0; k < 4; ++k) {
    int cid = tid + 256 * k;
    int px = cid >> 4, part = cid & 15;
    f16x8 v;
#pragma unroll
    for (int j = 0; j < 8; ++j) v[j] = (_Float16)t[px][part * 8 + j];
    *(f16x8*)&ob[(size_t)px * C_ + part * 8] = v;
  }
}

// --- Kernel A (MFMA): 1x1 conv 128->32 + bias -> off1t[b][px][32] fp16 ---
__global__ __launch_bounds__(256, 4) void k_off1m(
    const _Float16* __restrict__ xT, const _Float16* __restrict__ wo1H,
    const float* __restrict__ bo1, _Float16* __restrict__ off1t) {
  __shared__ float clds[32][257];
  int bid = blockIdx.x;                       // 576, %8==0
  int swz = (bid & 7) * (B_ * BPI / 8) + (bid >> 3);
  int b = swz / BPI, p0 = (swz % BPI) * 256;
  int tid = threadIdx.x;
  int lane = tid & 63, wv_ = tid >> 6;
  int lr = lane & 15, lk = lane >> 4;

  f32x4 acc[4][2];
#pragma unroll
  for (int mt = 0; mt < 4; ++mt)
#pragma unroll
    for (int nt = 0; nt < 2; ++nt) acc[mt][nt] = (f32x4){0.f, 0.f, 0.f, 0.f};

  const _Float16* xb = xT + ((size_t)b * HW_ + p0) * C_;
#pragma unroll
  for (int kk = 0; kk < 4; ++kk) {
    f16x8 afr[4];
#pragma unroll
    for (int mt = 0; mt < 4; ++mt)
      afr[mt] = *(const f16x8*)&xb[(size_t)((wv_ * 4 + mt) * 16 + lr) * C_ +
                                   kk * 32 + lk * 8];
#pragma unroll
    for (int nt = 0; nt < 2; ++nt) {
      f16x8 bfr = *(const f16x8*)&wo1H[(nt * 16 + lr) * C_ + kk * 32 + lk * 8];
#pragma unroll
      for (int mt = 0; mt < 4; ++mt)
        acc[mt][nt] = __builtin_amdgcn_mfma_f32_16x16x32_f16(afr[mt], bfr,
                                                             acc[mt][nt], 0, 0, 0);
    }
  }
#pragma unroll
  for (int nt = 0; nt < 2; ++nt)
#pragma unroll
    for (int mt = 0; mt < 4; ++mt)
#pragma unroll
      for (int r = 0; r < 4; ++r)
        clds[nt * 16 + lr][(wv_ * 4 + mt) * 16 + lk * 4 + r] = acc[mt][nt][r];
  __syncthreads();
  _Float16* orow = off1t + ((size_t)b * HW_ + p0 + tid) * 32;
#pragma unroll
  for (int q = 0; q < 4; ++q) {
    f16x8 v;
#pragma unroll
    for (int j = 0; j < 8; ++j)
      v[j] = (_Float16)(clds[q * 8 + j][tid] + bo1[q * 8 + j]);
    *(f16x8*)&orow[q * 8] = v;   // 64B/thread contiguous
  }
}

// --- Kernel B (MFMA): 3x3 dil(2) conv -> PACKED sample records ---
// srec[b][g][pos] (8B): w0 = base(14b) | dx<<14 | dy<<15 | w00(f16)<<16,
//                       w1 = w01(f16) | w10(f16)<<16.  (w11 derived: 1-Σ)
__global__ __launch_bounds__(256, 4) void k_coordsm(
    const _Float16* __restrict__ off1t, const _Float16* __restrict__ wo2H,
    uint2* __restrict__ srec) {
  __shared__ float clds[32][257];
  int bid = blockIdx.x;
  int swz = (bid & 7) * (B_ * BPI / 8) + (bid >> 3);
  int b = swz / BPI, p0 = (swz % BPI) * 256;
  int tid = threadIdx.x;
  int lane = tid & 63, wv_ = tid >> 6;
  int lr = lane & 15, lk = lane >> 4;

  f32x4 acc[4][2];
#pragma unroll
  for (int mt = 0; mt < 4; ++mt)
#pragma unroll
    for (int nt = 0; nt < 2; ++nt) acc[mt][nt] = (f32x4){0.f, 0.f, 0.f, 0.f};

  const _Float16* ob = off1t + (size_t)b * HW_ * 32;
  int hh[4], ww[4];
#pragma unroll
  for (int mt = 0; mt < 4; ++mt) {
    int px = p0 + (wv_ * 4 + mt) * 16 + lr;
    hh[mt] = px / W_;
    ww[mt] = px % W_;
  }
#pragma unroll
  for (int tap = 0; tap < 9; ++tap) {
    int dy2 = (tap / 3 - 1) * 2, dx2 = (tap % 3 - 1) * 2;
    f16x8 afr[4];
#pragma unroll
    for (int mt = 0; mt < 4; ++mt) {
      int h2 = hh[mt] + dy2, w2 = ww[mt] + dx2;
      f16x8 a = {};
      if ((unsigned)h2 < (unsigned)H_ && (unsigned)w2 < (unsigned)W_)
        a = *(const f16x8*)&ob[(size_t)(h2 * W_ + w2) * 32 + lk * 8];
      afr[mt] = a;
    }
#pragma unroll
    for (int nt = 0; nt < 2; ++nt) {
      f16x8 bfr = *(const f16x8*)&wo2H[(nt * 16 + lr) * 288 + tap * 32 + lk * 8];
#pragma unroll
      for (int mt = 0; mt < 4; ++mt)
        acc[mt][nt] = __builtin_amdgcn_mfma_f32_16x16x32_f16(afr[mt], bfr,
                                                             acc[mt][nt], 0, 0, 0);
    }
  }
#pragma unroll
  for (int nt = 0; nt < 2; ++nt)
#pragma unroll
    for (int mt = 0; mt < 4; ++mt)
#pragma unroll
      for (int r = 0; r < 4; ++r)
        clds[nt * 16 + lr][(wv_ * 4 + mt) * 16 + lk * 4 + r] = acc[mt][nt][r];
  __syncthreads();

  int px = p0 + tid;
  int h = px / W_, w = px % W_;
  float cwv = (float)w + sinf((float)M_PI * (float)(w + 1) / (float)W_);
  float chv = (float)h + sinf((float)M_PI * (float)(h + 1) / (float)H_);
  uint2* sb = srec + (size_t)b * G_ * HWO_;
#pragma unroll
  for (int g = 0; g < G_; ++g) {
#pragma unroll
    for (int sh = 0; sh < S_; ++sh) {
#pragma unroll
      for (int sw = 0; sw < S_; ++sw) {
        int idx = g * 4 + sh * 2 + sw;
        float offx = clds[idx][tid] * 0.25f + (sw ? 0.25f : -0.25f);
        float offy = clds[16 + idx][tid] * 0.25f + (sh ? 0.25f : -0.25f);
        float ix = fminf(fmaxf(cwv + offx - 0.5f, 0.f), (float)(W_ - 1));
        float iy = fminf(fmaxf(chv + offy - 0.5f, 0.f), (float)(H_ - 1));
        float x0f = floorf(ix), y0f = floorf(iy);
        float wx = ix - x0f, wy = iy - y0f;
        int x0 = (int)x0f, y0 = (int)y0f;       // in [0, 95]
        unsigned dx = (x0 < W_ - 1) ? 1u : 0u;
        unsigned dy = (y0 < H_ - 1) ? 1u : 0u;
        unsigned base = (unsigned)(y0 * W_ + x0);  // < 9216 < 2^14
        unsigned short u00 = h2u((_Float16)((1.f - wx) * (1.f - wy)));
        unsigned short u01 = h2u((_Float16)(wx * (1.f - wy)));
        unsigned short u10 = h2u((_Float16)((1.f - wx) * wy));
        uint2 rec;
        rec.x = base | (dx << 14) | (dy << 15) | ((unsigned)u00 << 16);
        rec.y = (unsigned)u01 | ((unsigned)u10 << 16);
        sb[(size_t)g * HWO_ + (2 * h + sh) * WO_ + (2 * w + sw)] = rec;
      }
    }
  }
}

// --- Kernel S: grid_sample (packed srec) + dw3x3+BN+ReLU -> y quarter-plane --
// R17 structure (6 blocks/CU). Sampling per item: 8B rec load + 3 unpacks +
// 4 ptr adds + 4 f16x8 loads + 4 pk_fma — per-position transform math now
// done once in k_coordsm instead of 4x here.
__global__ __launch_bounds__(256, 6) void k_sample(
    const _Float16* __restrict__ xT, const uint2* __restrict__ srec,
    const _Float16* __restrict__ wdwSh, const _Float16* __restrict__ bias2h,
    _Float16* __restrict__ y, int b0, int nimg) {
  __shared__ __align__(16) _Float16 up4[4 * NPOS * 8 + 832];  // 23424 B

  int NWG = nimg * TILES;
  int bid = blockIdx.x;
  int swz = (bid & 7) * (NWG >> 3) + (bid >> 3);  // NWG % 8 == 0 always
  int bl = swz / TILES;
  int b = b0 + bl;
  int t = swz % TILES;
  int oh0 = (t / (WO_ / TW_)) * TH_;
  int ow0 = (t % (WO_ / TW_)) * TW_;
  int tid = threadIdx.x;
  int py = tid >> 5, px = tid & 31;
  int p_out = (oh0 + py) * WO_ + ow0 + px;

  const _Float16* xbase = xT + (size_t)b * HW_ * C_;
  for (int g = 0; g < G_; ++g) {
    __syncthreads();  // protects up4 reuse across g
    const uint2* sbase = srec + ((size_t)b * G_ + g) * HWO_;
    const _Float16* xg = xbase + g * CPG_;
    // ---- sampling: 6 statically-unrolled rounds of (position, octet) ----
#pragma unroll
    for (int r = 0; r < 6; ++r) {
      int wi = tid + r * 256;
      if (r == 5 && wi >= NITEM) continue;   // exec-mask guard, last round only
      int p = wi >> 2, cq = wi & 3;
      int hy = oh0 + p / HALO_W - 1;
      int hx = ow0 + p % HALO_W - 1;
      f16x8 v = {};
      if (hy >= 0 && hy < HO_ && hx >= 0 && hx < WO_) {
        uint2 rc = sbase[(size_t)hy * WO_ + hx];
        int base = rc.x & 0x3FFFu;
        int dxC = ((rc.x >> 14) & 1u) << 7;            // dx * 128
        int dyC = ((rc.x >> 15) & 1u) * 12288;         // dy * 96 * 128
        _Float16 w00 = u2h((unsigned short)(rc.x >> 16));
        _Float16 w01 = u2h((unsigned short)(rc.y & 0xffffu));
        _Float16 w10 = u2h((unsigned short)(rc.y >> 16));
        float w11f = 1.f - (float)w00 - (float)w01 - (float)w10;
        const _Float16* a00p = xg + cq * 8 + (size_t)base * C_;
        f16x8 a00 = *(const f16x8*)a00p;
        f16x8 a01 = *(const f16x8*)(a00p + dxC);
        f16x8 a10 = *(const f16x8*)(a00p + dyC);
        f16x8 a11 = *(const f16x8*)(a00p + dyC + dxC);
        v = a00 * splat8(w00) + a01 * splat8(w01) + a10 * splat8(w10) +
            a11 * splat8((_Float16)w11f);              // v_pk_fma_f16
      }
      *(f16x8*)&up4[((size_t)cq * NPOS + p) * 8] = v;  // aligned b128 store
    }
    __syncthreads();

    // ---- dw3x3+BN+ReLU: packed fp16 accumulation (v_pk_fma_f16) ----
#pragma unroll
    for (int q = 0; q < 4; ++q) {
      f16x8 acc = *(const f16x8*)&bias2h[g * CPG_ + q * 8];   // uniform s_load
#pragma unroll
      for (int tt = 0; tt < 9; ++tt) {
        int dy = tt / 3, dx = tt % 3;
        f16x8 pk = *(const f16x8*)
            &up4[((size_t)q * NPOS + (py + dy) * HALO_W + px + dx) * 8];
        f16x8 wv = *(const f16x8*)&wdwSh[tt * C_ + g * CPG_ + q * 8];  // s_load
        acc += pk * wv;   // 4x v_pk_fma_f16
      }
      f16x8 yv;
#pragma unroll
      for (int j = 0; j < 8; ++j)
        yv[j] = acc[j] > (_Float16)0.f ? acc[j] : (_Float16)0.f;  // pk_max
      // y quarter-plane layout: lanes write 16B contiguous (full lines)
      *(f16x8*)&y[(((size_t)(bl * G_ + g) * 4 + q) * HWO_ + p_out) * 8] = yv;
    }
  }
}

// --- Kernel G: streaming GEMM y @ W[128][64] -> out (quarter-plane y) ---
__global__ __launch_bounds__(256, 4) void k_gemm(
    const _Float16* __restrict__ y, const _Float16* __restrict__ wpwH,
    const float* __restrict__ bpw, float* __restrict__ out, int b0, int nimg) {
  __shared__ float clds16[16][257];

  int NWG = nimg * TILES;
  int bid = blockIdx.x;
  int swz = (bid & 7) * (NWG >> 3) + (bid >> 3);
  int bl = swz / TILES;
  int b = b0 + bl;
  int p0 = (swz % TILES) * 256;
  int tid = threadIdx.x;
  int lane = tid & 63, wv_ = tid >> 6;
  int lr = lane & 15, lk = lane >> 4;

  f32x4 acc[4][4];
#pragma unroll
  for (int mt = 0; mt < 4; ++mt)
#pragma unroll
    for (int nt = 0; nt < 4; ++nt) acc[mt][nt] = (f32x4){0.f, 0.f, 0.f, 0.f};

  const _Float16* ybl = y + (size_t)bl * IMG_YF16;
#pragma unroll
  for (int kk = 0; kk < 4; ++kk) {
    f16x8 afr[4];
#pragma unroll
    for (int mt = 0; mt < 4; ++mt)
      afr[mt] = *(const f16x8*)&ybl[(((size_t)(kk * 4 + lk) * HWO_) + p0 +
                                     (wv_ * 4 + mt) * 16 + lr) * 8];
#pragma unroll
    for (int nt = 0; nt < 4; ++nt) {
      f16x8 bfr = *(const f16x8*)&wpwH[(nt * 16 + lr) * C_ + kk * CPG_ + lk * 8];
#pragma unroll
      for (int mt = 0; mt < 4; ++mt)
        acc[mt][nt] = __builtin_amdgcn_mfma_f32_16x16x32_f16(afr[mt], bfr,
                                                             acc[mt][nt], 0, 0, 0);
    }
  }
#pragma unroll
  for (int hq = 0; hq < 4; ++hq) {
    if (hq) __syncthreads();
#pragma unroll
    for (int mt = 0; mt < 4; ++mt) {
#pragma unroll
      for (int r = 0; r < 4; ++r)
        clds16[lr][(wv_ * 4 + mt) * 16 + lk * 4 + r] = acc[mt][hq][r];
    }
    __syncthreads();
#pragma unroll
    for (int i = 0; i < 16; ++i) {
      int o = hq * 16 + i;
      out[((size_t)b * COUT_ + o) * HWO_ + p0 + tid] = clds16[i][tid] + bpw[o];
    }
  }
}

extern "C" void kernel_launch(void* const* d_in, const int* in_sizes, int n_in,
                              void* d_out, int out_size, void* d_ws, size_t ws_size,
                              hipStream_t stream) {
  const float* x        = (const float*)d_in[0];
  const float* Wo1      = (const float*)d_in[1];
  const float* bo1      = (const float*)d_in[2];
  const float* Wo2      = (const float*)d_in[3];
  const float* Wdw      = (const float*)d_in[4];
  const float* bn_gamma = (const float*)d_in[5];
  const float* bn_beta  = (const float*)d_in[6];
  const float* bn_mean  = (const float*)d_in[7];
  const float* bn_var   = (const float*)d_in[8];
  const float* Wpw      = (const float*)d_in[9];
  const float* bpw      = (const float*)d_in[10];
  float* out = (float*)d_out;

  float* ws = (float*)d_ws;
  _Float16* xT     = (_Float16*)(ws + WS_XT);
  _Float16* off1t  = (_Float16*)(ws + WS_OFF1T);
  uint2* srec      = (uint2*)(ws + WS_SREC);
  _Float16* wpwH   = (_Float16*)(ws + WS_WPWH);
  _Float16* wo1H   = (_Float16*)(ws + WS_WO1H);
  _Float16* wo2H   = (_Float16*)(ws + WS_WO2H);
  _Float16* wdwSh  = (_Float16*)(ws + WS_WDWSH);
  _Float16* bias2h = (_Float16*)(ws + WS_BIAS2H);

  // y tiers: full/mid use dedicated region; small tier (1 img) aliases
  // off1t (dead after k_coordsm; 1-img y fits in off1t region exactly).
  int chunk;
  _Float16* yb;
  if (ws_size >= NEED_FULL)      { chunk = 16; yb = (_Float16*)(ws + WS_Y); }
  else if (ws_size >= NEED_MID)  { chunk = 8;  yb = (_Float16*)(ws + WS_Y); }
  else                           { chunk = 1;  yb = (_Float16*)(ws + WS_OFF1T); }

  k_prep   <<<(PREP_N + 255) / 256, 256, 0, stream>>>(
      Wpw, Wo1, Wo2, Wdw, bn_gamma, bn_beta, bn_mean, bn_var,
      wpwH, wo1H, wo2H, wdwSh, bias2h);
  k_xpose  <<<B_ * XPB, 256, 0, stream>>>(x, xT);
  k_off1m  <<<B_ * BPI, 256, 0, stream>>>(xT, wo1H, bo1, off1t);
  k_coordsm<<<B_ * BPI, 256, 0, stream>>>(off1t, wo2H, srec);
  for (int c0 = 0; c0 < B_; c0 += chunk) {
    k_sample<<<chunk * TILES, 256, 0, stream>>>(xT, srec, wdwSh, bias2h, yb,
                                                c0, chunk);
    k_gemm  <<<chunk * TILES, 256, 0, stream>>>(yb, wpwH, bpw, out, c0, chunk);
  }
}

// Round 21
// 181.083 us; speedup vs baseline: 1.7443x; 1.0307x over previous
//
#include <hip/hip_runtime.h>
#include <math.h>

typedef _Float16 f16x8 __attribute__((ext_vector_type(8)));
typedef _Float16 f16x2 __attribute__((ext_vector_type(2)));
typedef float f32x4 __attribute__((ext_vector_type(4)));

namespace {
constexpr int B_ = 16, C_ = 128, H_ = 96, W_ = 96;
constexpr int HW_ = H_ * W_;      // 9216
constexpr int G_ = 4, S_ = 2;
constexpr int CO_ = 32;
constexpr int COUT_ = 64;
constexpr int HO_ = 192, WO_ = 192;
constexpr int HWO_ = HO_ * WO_;   // 36864
constexpr int CPG_ = C_ / G_;     // 32
constexpr int TH_ = 8, TW_ = 32;
constexpr int HALO_H = TH_ + 2, HALO_W = TW_ + 2;
constexpr int NPOS = HALO_H * HALO_W;   // 340
constexpr int NITEM = NPOS * 4;         // 1360
constexpr int TILES = (WO_ / TW_) * (HO_ / TH_);  // 144
constexpr int BPI = HW_ / 256;    // 36 blocks/image for 96x96 MFMA kernels
constexpr int XPB = HW_ / 64;     // 144 xoff blocks/image

// ws float offsets (f16[N] = N/2 floats)
constexpr size_t WS_XT     = 0;                    // f16[18874368] = 9437184 f
constexpr size_t WS_OFF1T  = 9437184;              // f16[4718592]  = 2359296 f
constexpr size_t WS_SREC   = 11796480;             // uint2[B*G*HWO] = 4718592 f
constexpr size_t WS_WPWH   = 16515072;             // f16[8192] = 4096 f
constexpr size_t WS_WO1H   = 16519168;             // f16[4096] = 2048 f
constexpr size_t WS_WO2H   = 16521216;             // f16[9216] = 4608 f
constexpr size_t WS_WDWSH  = 16525824;             // f16[1152] = 576 f
constexpr size_t WS_BIAS2H = 16526400;             // f16[128]  = 64 f
constexpr size_t WS_Y      = 16526464;
constexpr size_t IMG_YF16  = (size_t)G_ * 4 * HWO_ * 8;   // 4718592 f16 / image
constexpr size_t Y_FULL_F  = (size_t)B_ * IMG_YF16 / 2;   // 37748736 f
constexpr size_t NEED_FULL = (WS_Y + Y_FULL_F) * 4;       // ~217.1 MB
constexpr size_t NEED_MID  = (WS_Y + Y_FULL_F / 2) * 4;   // ~141.6 MB

constexpr int PREP_N = 8192 + 4096 + 9216 + 1152 + 128;   // 22784
}

__device__ __forceinline__ f16x8 splat8(_Float16 s) {
  return (f16x8){s, s, s, s, s, s, s, s};
}
__device__ __forceinline__ unsigned short h2u(_Float16 h) {
  union { unsigned short u; _Float16 h; } c; c.h = h; return c.u;
}
__device__ __forceinline__ _Float16 u2h(unsigned short u) {
  union { unsigned short u; _Float16 h; } c; c.u = u; return c.h;
}

// --- Kernel P: fp16 casts (Wpw, Wo1, Wo2 k-reordered, BN-folded dw+bias) ---
__global__ __launch_bounds__(256) void k_prep(
    const float* __restrict__ Wpw, const float* __restrict__ Wo1,
    const float* __restrict__ Wo2, const float* __restrict__ Wdw,
    const float* __restrict__ bn_gamma, const float* __restrict__ bn_beta,
    const float* __restrict__ bn_mean, const float* __restrict__ bn_var,
    _Float16* __restrict__ wpwH, _Float16* __restrict__ wo1H,
    _Float16* __restrict__ wo2H, _Float16* __restrict__ wdwSh,
    _Float16* __restrict__ bias2h) {
  int i = blockIdx.x * 256 + threadIdx.x;
  if (i < 8192) {
    wpwH[i] = (_Float16)Wpw[i];
  } else if (i < 8192 + 4096) {
    int j = i - 8192;
    wo1H[j] = (_Float16)Wo1[j];                 // keep [o][c]
  } else if (i < 8192 + 4096 + 9216) {
    int j = i - 8192 - 4096;                    // dst [o][tap*32+ci]
    int o = j / 288, r = j % 288;
    int tap = r / 32, ci = r % 32;
    wo2H[j] = (_Float16)Wo2[o * 288 + ci * 9 + tap];
  } else if (i < 8192 + 4096 + 9216 + 1152) {
    int j = i - 8192 - 4096 - 9216;             // Wdw is [c][9]
    int c = j / 9, t = j % 9;
    float sc = bn_gamma[c] * rsqrtf(bn_var[c] + 1e-5f);
    wdwSh[t * C_ + c] = (_Float16)(Wdw[j] * sc);
  } else if (i < PREP_N) {
    int c = i - (8192 + 4096 + 9216 + 1152);
    float sc = bn_gamma[c] * rsqrtf(bn_var[c] + 1e-5f);
    bias2h[c] = (_Float16)(bn_beta[c] - bn_mean[c] * sc);
  }
}

// --- Kernel XO: fused transpose (x f32 -> xT f16) + 1x1 conv 128->32 MFMA ---
// 64 px per block. LDS t[64][130] f32 (33.3 KB -> 4 blocks/CU); off1 epilogue
// overlays the same buffer after a barrier.
__global__ __launch_bounds__(256, 4) void k_xoff(
    const float* __restrict__ x, const _Float16* __restrict__ wo1H,
    const float* __restrict__ bo1, _Float16* __restrict__ xT,
    _Float16* __restrict__ off1t) {
  __shared__ float t[64][130];   // 33280 B; overlaid by cl[32][65] later
  int bid = blockIdx.x;          // B*XPB = 2304, %8==0
  int swz = (bid & 7) * (B_ * XPB / 8) + (bid >> 3);
  int b = swz / XPB, px0 = (swz % XPB) * 64;
  int tid = threadIdx.x;
  int lane = tid & 63, wv = tid >> 6;
  int lr = lane & 15, lk = lane >> 4;

  const float* xb = x + (size_t)b * C_ * HW_ + px0 + lane;
  for (int c = wv; c < C_; c += 4) t[lane][c] = xb[(size_t)c * HW_];
  __syncthreads();

  // xT write (as before)
  _Float16* ob = xT + ((size_t)b * HW_ + px0) * C_;
#pragma unroll
  for (int k = 0; k < 4; ++k) {
    int cid = tid + 256 * k;
    int px = cid >> 4, part = cid & 15;
    f16x8 v;
#pragma unroll
    for (int j = 0; j < 8; ++j) v[j] = (_Float16)t[px][part * 8 + j];
    *(f16x8*)&ob[(size_t)px * C_ + part * 8] = v;
  }

  // off1 MFMA: wave wv owns px rows wv*16..wv*16+15 (M=16, N=32, K=128)
  f32x4 acc[2];
  acc[0] = (f32x4){0.f, 0.f, 0.f, 0.f};
  acc[1] = (f32x4){0.f, 0.f, 0.f, 0.f};
#pragma unroll
  for (int kk = 0; kk < 4; ++kk) {
    f16x8 afr;
#pragma unroll
    for (int j = 0; j < 8; ++j)
      afr[j] = (_Float16)t[wv * 16 + lr][kk * 32 + lk * 8 + j];
#pragma unroll
    for (int nt = 0; nt < 2; ++nt) {
      f16x8 bfr = *(const f16x8*)&wo1H[(nt * 16 + lr) * C_ + kk * 32 + lk * 8];
      acc[nt] = __builtin_amdgcn_mfma_f32_16x16x32_f16(afr, bfr, acc[nt], 0, 0, 0);
    }
  }
  __syncthreads();   // done reading t
  float (*cl)[65] = (float(*)[65])t;   // [32 ch][64 px] overlay, 8320 f32
#pragma unroll
  for (int nt = 0; nt < 2; ++nt)
#pragma unroll
    for (int r = 0; r < 4; ++r)
      cl[nt * 16 + lr][wv * 16 + lk * 4 + r] = acc[nt][r];
  __syncthreads();
  {
    int px = tid >> 2, part = tid & 3;
    f16x8 v;
#pragma unroll
    for (int j = 0; j < 8; ++j)
      v[j] = (_Float16)(cl[part * 8 + j][px] + bo1[part * 8 + j]);
    *(f16x8*)&off1t[((size_t)b * HW_ + px0 + px) * 32 + part * 8] = v;
  }
}

// --- Kernel B (MFMA): 3x3 dil(2) conv -> PACKED sample records ---
// srec[b][g][pos] (8B): w0 = base(14b) | dx<<14 | dy<<15 | w00(f16)<<16,
//                       w1 = w01(f16) | w10(f16)<<16.  (w11 derived: 1-Σ)
__global__ __launch_bounds__(256, 4) void k_coordsm(
    const _Float16* __restrict__ off1t, const _Float16* __restrict__ wo2H,
    uint2* __restrict__ srec) {
  __shared__ float clds[32][257];
  int bid = blockIdx.x;
  int swz = (bid & 7) * (B_ * BPI / 8) + (bid >> 3);
  int b = swz / BPI, p0 = (swz % BPI) * 256;
  int tid = threadIdx.x;
  int lane = tid & 63, wv_ = tid >> 6;
  int lr = lane & 15, lk = lane >> 4;

  f32x4 acc[4][2];
#pragma unroll
  for (int mt = 0; mt < 4; ++mt)
#pragma unroll
    for (int nt = 0; nt < 2; ++nt) acc[mt][nt] = (f32x4){0.f, 0.f, 0.f, 0.f};

  const _Float16* ob = off1t + (size_t)b * HW_ * 32;
  int hh[4], ww[4];
#pragma unroll
  for (int mt = 0; mt < 4; ++mt) {
    int px = p0 + (wv_ * 4 + mt) * 16 + lr;
    hh[mt] = px / W_;
    ww[mt] = px % W_;
  }
#pragma unroll
  for (int tap = 0; tap < 9; ++tap) {
    int dy2 = (tap / 3 - 1) * 2, dx2 = (tap % 3 - 1) * 2;
    f16x8 afr[4];
#pragma unroll
    for (int mt = 0; mt < 4; ++mt) {
      int h2 = hh[mt] + dy2, w2 = ww[mt] + dx2;
      f16x8 a = {};
      if ((unsigned)h2 < (unsigned)H_ && (unsigned)w2 < (unsigned)W_)
        a = *(const f16x8*)&ob[(size_t)(h2 * W_ + w2) * 32 + lk * 8];
      afr[mt] = a;
    }
#pragma unroll
    for (int nt = 0; nt < 2; ++nt) {
      f16x8 bfr = *(const f16x8*)&wo2H[(nt * 16 + lr) * 288 + tap * 32 + lk * 8];
#pragma unroll
      for (int mt = 0; mt < 4; ++mt)
        acc[mt][nt] = __builtin_amdgcn_mfma_f32_16x16x32_f16(afr[mt], bfr,
                                                             acc[mt][nt], 0, 0, 0);
    }
  }
#pragma unroll
  for (int nt = 0; nt < 2; ++nt)
#pragma unroll
    for (int mt = 0; mt < 4; ++mt)
#pragma unroll
      for (int r = 0; r < 4; ++r)
        clds[nt * 16 + lr][(wv_ * 4 + mt) * 16 + lk * 4 + r] = acc[mt][nt][r];
  __syncthreads();

  int px = p0 + tid;
  int h = px / W_, w = px % W_;
  float cwv = (float)w + sinf((float)M_PI * (float)(w + 1) / (float)W_);
  float chv = (float)h + sinf((float)M_PI * (float)(h + 1) / (float)H_);
  uint2* sb = srec + (size_t)b * G_ * HWO_;
#pragma unroll
  for (int g = 0; g < G_; ++g) {
#pragma unroll
    for (int sh = 0; sh < S_; ++sh) {
#pragma unroll
      for (int sw = 0; sw < S_; ++sw) {
        int idx = g * 4 + sh * 2 + sw;
        float offx = clds[idx][tid] * 0.25f + (sw ? 0.25f : -0.25f);
        float offy = clds[16 + idx][tid] * 0.25f + (sh ? 0.25f : -0.25f);
        float ix = fminf(fmaxf(cwv + offx - 0.5f, 0.f), (float)(W_ - 1));
        float iy = fminf(fmaxf(chv + offy - 0.5f, 0.f), (float)(H_ - 1));
        float x0f = floorf(ix), y0f = floorf(iy);
        float wx = ix - x0f, wy = iy - y0f;
        int x0 = (int)x0f, y0 = (int)y0f;       // in [0, 95]
        unsigned dx = (x0 < W_ - 1) ? 1u : 0u;
        unsigned dy = (y0 < H_ - 1) ? 1u : 0u;
        unsigned base = (unsigned)(y0 * W_ + x0);  // < 9216 < 2^14
        unsigned short u00 = h2u((_Float16)((1.f - wx) * (1.f - wy)));
        unsigned short u01 = h2u((_Float16)(wx * (1.f - wy)));
        unsigned short u10 = h2u((_Float16)((1.f - wx) * wy));
        uint2 rec;
        rec.x = base | (dx << 14) | (dy << 15) | ((unsigned)u00 << 16);
        rec.y = (unsigned)u01 | ((unsigned)u10 << 16);
        sb[(size_t)g * HWO_ + (2 * h + sh) * WO_ + (2 * w + sw)] = rec;
      }
    }
  }
}

// --- Kernel S: grid_sample (packed srec, BRANCHLESS) + dw3x3+BN+ReLU -> y ---
// OOB handled by clamped srec address + select-zero on the result, so the
// 6 unrolled rounds are straight-line -> compiler can pipeline all loads.
__global__ __launch_bounds__(256, 6) void k_sample(
    const _Float16* __restrict__ xT, const uint2* __restrict__ srec,
    const _Float16* __restrict__ wdwSh, const _Float16* __restrict__ bias2h,
    _Float16* __restrict__ y, int b0, int nimg) {
  __shared__ __align__(16) _Float16 up4[4 * NPOS * 8 + 832];  // 23424 B

  int NWG = nimg * TILES;
  int bid = blockIdx.x;
  int swz = (bid & 7) * (NWG >> 3) + (bid >> 3);  // NWG % 8 == 0 always
  int bl = swz / TILES;
  int b = b0 + bl;
  int t = swz % TILES;
  int oh0 = (t / (WO_ / TW_)) * TH_;
  int ow0 = (t % (WO_ / TW_)) * TW_;
  int tid = threadIdx.x;
  int py = tid >> 5, px = tid & 31;
  int p_out = (oh0 + py) * WO_ + ow0 + px;

  const _Float16* xbase = xT + (size_t)b * HW_ * C_;
  for (int g = 0; g < G_; ++g) {
    __syncthreads();  // protects up4 reuse across g
    const uint2* sbase = srec + ((size_t)b * G_ + g) * HWO_;
    const _Float16* xg = xbase + g * CPG_;
    // ---- sampling: 6 statically-unrolled BRANCHLESS rounds ----
#pragma unroll
    for (int r = 0; r < 6; ++r) {
      int wi = tid + r * 256;
      if (r == 5 && wi >= NITEM) continue;   // exec-mask guard, last round only
      int p = wi >> 2, cq = wi & 3;
      int hy = oh0 + p / HALO_W - 1;
      int hx = ow0 + p % HALO_W - 1;
      bool inb = ((unsigned)hy < (unsigned)HO_) && ((unsigned)hx < (unsigned)WO_);
      int hyc = min(max(hy, 0), HO_ - 1);
      int hxc = min(max(hx, 0), WO_ - 1);
      uint2 rc = sbase[(size_t)hyc * WO_ + hxc];
      int base = rc.x & 0x3FFFu;
      int dxC = ((rc.x >> 14) & 1u) << 7;            // dx * 128
      int dyC = ((rc.x >> 15) & 1u) * 12288;         // dy * 96 * 128
      _Float16 w00 = u2h((unsigned short)(rc.x >> 16));
      _Float16 w01 = u2h((unsigned short)(rc.y & 0xffffu));
      _Float16 w10 = u2h((unsigned short)(rc.y >> 16));
      float w11f = 1.f - (float)w00 - (float)w01 - (float)w10;
      const _Float16* a00p = xg + cq * 8 + (size_t)base * C_;
      f16x8 a00 = *(const f16x8*)a00p;
      f16x8 a01 = *(const f16x8*)(a00p + dxC);
      f16x8 a10 = *(const f16x8*)(a00p + dyC);
      f16x8 a11 = *(const f16x8*)(a00p + dyC + dxC);
      f16x8 v = a00 * splat8(w00) + a01 * splat8(w01) + a10 * splat8(w10) +
                a11 * splat8((_Float16)w11f);        // v_pk_fma_f16
      if (!inb) v = (f16x8){};                       // select-zero (no branch)
      *(f16x8*)&up4[((size_t)cq * NPOS + p) * 8] = v;  // aligned b128 store
    }
    __syncthreads();

    // ---- dw3x3+BN+ReLU: packed fp16 accumulation (v_pk_fma_f16) ----
#pragma unroll
    for (int q = 0; q < 4; ++q) {
      f16x8 acc = *(const f16x8*)&bias2h[g * CPG_ + q * 8];   // uniform s_load
#pragma unroll
      for (int tt = 0; tt < 9; ++tt) {
        int dy = tt / 3, dx = tt % 3;
        f16x8 pk = *(const f16x8*)
            &up4[((size_t)q * NPOS + (py + dy) * HALO_W + px + dx) * 8];
        f16x8 wv = *(const f16x8*)&wdwSh[tt * C_ + g * CPG_ + q * 8];  // s_load
        acc += pk * wv;   // 4x v_pk_fma_f16
      }
      f16x8 yv;
#pragma unroll
      for (int j = 0; j < 8; ++j)
        yv[j] = acc[j] > (_Float16)0.f ? acc[j] : (_Float16)0.f;  // pk_max
      // y quarter-plane layout: lanes write 16B contiguous (full lines)
      *(f16x8*)&y[(((size_t)(bl * G_ + g) * 4 + q) * HWO_ + p_out) * 8] = yv;
    }
  }
}

// --- Kernel G: streaming GEMM y @ W[128][64] -> out (quarter-plane y) ---
__global__ __launch_bounds__(256, 4) void k_gemm(
    const _Float16* __restrict__ y, const _Float16* __restrict__ wpwH,
    const float* __restrict__ bpw, float* __restrict__ out, int b0, int nimg) {
  __shared__ float clds16[16][257];

  int NWG = nimg * TILES;
  int bid = blockIdx.x;
  int swz = (bid & 7) * (NWG >> 3) + (bid >> 3);
  int bl = swz / TILES;
  int b = b0 + bl;
  int p0 = (swz % TILES) * 256;
  int tid = threadIdx.x;
  int lane = tid & 63, wv_ = tid >> 6;
  int lr = lane & 15, lk = lane >> 4;

  f32x4 acc[4][4];
#pragma unroll
  for (int mt = 0; mt < 4; ++mt)
#pragma unroll
    for (int nt = 0; nt < 4; ++nt) acc[mt][nt] = (f32x4){0.f, 0.f, 0.f, 0.f};

  const _Float16* ybl = y + (size_t)bl * IMG_YF16;
#pragma unroll
  for (int kk = 0; kk < 4; ++kk) {
    f16x8 afr[4];
#pragma unroll
    for (int mt = 0; mt < 4; ++mt)
      afr[mt] = *(const f16x8*)&ybl[(((size_t)(kk * 4 + lk) * HWO_) + p0 +
                                     (wv_ * 4 + mt) * 16 + lr) * 8];
#pragma unroll
    for (int nt = 0; nt < 4; ++nt) {
      f16x8 bfr = *(const f16x8*)&wpwH[(nt * 16 + lr) * C_ + kk * CPG_ + lk * 8];
#pragma unroll
      for (int mt = 0; mt < 4; ++mt)
        acc[mt][nt] = __builtin_amdgcn_mfma_f32_16x16x32_f16(afr[mt], bfr,
                                                             acc[mt][nt], 0, 0, 0);
    }
  }
#pragma unroll
  for (int hq = 0; hq < 4; ++hq) {
    if (hq) __syncthreads();
#pragma unroll
    for (int mt = 0; mt < 4; ++mt) {
#pragma unroll
      for (int r = 0; r < 4; ++r)
        clds16[lr][(wv_ * 4 + mt) * 16 + lk * 4 + r] = acc[mt][hq][r];
    }
    __syncthreads();
#pragma unroll
    for (int i = 0; i < 16; ++i) {
      int o = hq * 16 + i;
      out[((size_t)b * COUT_ + o) * HWO_ + p0 + tid] = clds16[i][tid] + bpw[o];
    }
  }
}

extern "C" void kernel_launch(void* const* d_in, const int* in_sizes, int n_in,
                              void* d_out, int out_size, void* d_ws, size_t ws_size,
                              hipStream_t stream) {
  const float* x        = (const float*)d_in[0];
  const float* Wo1      = (const float*)d_in[1];
  const float* bo1      = (const float*)d_in[2];
  const float* Wo2      = (const float*)d_in[3];
  const float* Wdw      = (const float*)d_in[4];
  const float* bn_gamma = (const float*)d_in[5];
  const float* bn_beta  = (const float*)d_in[6];
  const float* bn_mean  = (const float*)d_in[7];
  const float* bn_var   = (const float*)d_in[8];
  const float* Wpw      = (const float*)d_in[9];
  const float* bpw      = (const float*)d_in[10];
  float* out = (float*)d_out;

  float* ws = (float*)d_ws;
  _Float16* xT     = (_Float16*)(ws + WS_XT);
  _Float16* off1t  = (_Float16*)(ws + WS_OFF1T);
  uint2* srec      = (uint2*)(ws + WS_SREC);
  _Float16* wpwH   = (_Float16*)(ws + WS_WPWH);
  _Float16* wo1H   = (_Float16*)(ws + WS_WO1H);
  _Float16* wo2H   = (_Float16*)(ws + WS_WO2H);
  _Float16* wdwSh  = (_Float16*)(ws + WS_WDWSH);
  _Float16* bias2h = (_Float16*)(ws + WS_BIAS2H);

  // y tiers: full/mid use dedicated region; small tier (1 img) aliases
  // off1t (dead after k_coordsm; 1-img y fits in off1t region exactly).
  int chunk;
  _Float16* yb;
  if (ws_size >= NEED_FULL)      { chunk = 16; yb = (_Float16*)(ws + WS_Y); }
  else if (ws_size >= NEED_MID)  { chunk = 8;  yb = (_Float16*)(ws + WS_Y); }
  else                           { chunk = 1;  yb = (_Float16*)(ws + WS_OFF1T); }

  k_prep   <<<(PREP_N + 255) / 256, 256, 0, stream>>>(
      Wpw, Wo1, Wo2, Wdw, bn_gamma, bn_beta, bn_mean, bn_var,
      wpwH, wo1H, wo2H, wdwSh, bias2h);
  k_xoff   <<<B_ * XPB, 256, 0, stream>>>(x, wo1H, bo1, xT, off1t);
  k_coordsm<<<B_ * BPI, 256, 0, stream>>>(off1t, wo2H, srec);
  for (int c0 = 0; c0 < B_; c0 += chunk) {
    k_sample<<<chunk * TILES, 256, 0, stream>>>(xT, srec, wdwSh, bias2h, yb,
                                                c0, chunk);
    k_gemm  <<<chunk * TILES, 256, 0, stream>>>(yb, wpwH, bpw, out, c0, chunk);
  }
}

// Round 22
// 163.816 us; speedup vs baseline: 1.9282x; 1.1054x over previous
//
#include <hip/hip_runtime.h>
#include <math.h>

typedef _Float16 f16x8 __attribute__((ext_vector_type(8)));
typedef _Float16 f16x2 __attribute__((ext_vector_type(2)));
typedef float f32x4 __attribute__((ext_vector_type(4)));

namespace {
constexpr int B_ = 16, C_ = 128, H_ = 96, W_ = 96;
constexpr int HW_ = H_ * W_;      // 9216
constexpr int G_ = 4, S_ = 2;
constexpr int CO_ = 32;
constexpr int COUT_ = 64;
constexpr int HO_ = 192, WO_ = 192;
constexpr int HWO_ = HO_ * WO_;   // 36864
constexpr int CPG_ = C_ / G_;     // 32
constexpr int TH_ = 8, TW_ = 32;
constexpr int HALO_H = TH_ + 2, HALO_W = TW_ + 2;
constexpr int NPOS = HALO_H * HALO_W;   // 340
constexpr int NITEM = NPOS * 4;         // 1360
constexpr int TILES = (WO_ / TW_) * (HO_ / TH_);  // 144
constexpr int BPI = HW_ / 256;    // 36 blocks/image for 96x96 MFMA kernels
constexpr int XPB = HW_ / 64;     // 144 xoff blocks/image

// ws float offsets (f16[N] = N/2 floats)
constexpr size_t WS_XT     = 0;                    // f16[18874368] = 9437184 f
constexpr size_t WS_OFF1T  = 9437184;              // f16[4718592]  = 2359296 f
constexpr size_t WS_SREC   = 11796480;             // uint2[B*G*HWO] = 4718592 f
constexpr size_t WS_WPWH   = 16515072;             // f16[8192] = 4096 f
constexpr size_t WS_WO1H   = 16519168;             // f16[4096] = 2048 f
constexpr size_t WS_WO2H   = 16521216;             // f16[9216] = 4608 f
constexpr size_t WS_WDWSH  = 16525824;             // f16[1152] = 576 f
constexpr size_t WS_BIAS2H = 16526400;             // f16[128]  = 64 f
constexpr size_t WS_Y      = 16526464;
constexpr size_t IMG_YF16  = (size_t)G_ * 4 * HWO_ * 8;   // 4718592 f16 / image
constexpr size_t Y_FULL_F  = (size_t)B_ * IMG_YF16 / 2;   // 37748736 f
constexpr size_t NEED_FULL = (WS_Y + Y_FULL_F) * 4;       // ~217.1 MB
constexpr size_t NEED_MID  = (WS_Y + Y_FULL_F / 2) * 4;   // ~141.6 MB

constexpr int PREP_N = 8192 + 4096 + 9216 + 1152 + 128;   // 22784
}

__device__ __forceinline__ f16x8 splat8(_Float16 s) {
  return (f16x8){s, s, s, s, s, s, s, s};
}
__device__ __forceinline__ unsigned short h2u(_Float16 h) {
  union { unsigned short u; _Float16 h; } c; c.h = h; return c.u;
}
__device__ __forceinline__ _Float16 u2h(unsigned short u) {
  union { unsigned short u; _Float16 h; } c; c.u = u; return c.h;
}

// --- Kernel P: fp16 casts (Wpw, Wo1, Wo2 k-reordered, BN-folded dw+bias) ---
__global__ __launch_bounds__(256) void k_prep(
    const float* __restrict__ Wpw, const float* __restrict__ Wo1,
    const float* __restrict__ Wo2, const float* __restrict__ Wdw,
    const float* __restrict__ bn_gamma, const float* __restrict__ bn_beta,
    const float* __restrict__ bn_mean, const float* __restrict__ bn_var,
    _Float16* __restrict__ wpwH, _Float16* __restrict__ wo1H,
    _Float16* __restrict__ wo2H, _Float16* __restrict__ wdwSh,
    _Float16* __restrict__ bias2h) {
  int i = blockIdx.x * 256 + threadIdx.x;
  if (i < 8192) {
    wpwH[i] = (_Float16)Wpw[i];
  } else if (i < 8192 + 4096) {
    int j = i - 8192;
    wo1H[j] = (_Float16)Wo1[j];                 // keep [o][c]
  } else if (i < 8192 + 4096 + 9216) {
    int j = i - 8192 - 4096;                    // dst [o][tap*32+ci]
    int o = j / 288, r = j % 288;
    int tap = r / 32, ci = r % 32;
    wo2H[j] = (_Float16)Wo2[o * 288 + ci * 9 + tap];
  } else if (i < 8192 + 4096 + 9216 + 1152) {
    int j = i - 8192 - 4096 - 9216;             // Wdw is [c][9]
    int c = j / 9, t = j % 9;
    float sc = bn_gamma[c] * rsqrtf(bn_var[c] + 1e-5f);
    wdwSh[t * C_ + c] = (_Float16)(Wdw[j] * sc);
  } else if (i < PREP_N) {
    int c = i - (8192 + 4096 + 9216 + 1152);
    float sc = bn_gamma[c] * rsqrtf(bn_var[c] + 1e-5f);
    bias2h[c] = (_Float16)(bn_beta[c] - bn_mean[c] * sc);
  }
}

// --- Kernel XO: fused transpose (x f32 -> xT f16) + 1x1 conv 128->32 MFMA ---
__global__ __launch_bounds__(256, 4) void k_xoff(
    const float* __restrict__ x, const _Float16* __restrict__ wo1H,
    const float* __restrict__ bo1, _Float16* __restrict__ xT,
    _Float16* __restrict__ off1t) {
  __shared__ float t[64][130];   // 33280 B; overlaid by cl[32][65] later
  int bid = blockIdx.x;          // B*XPB = 2304, %8==0
  int swz = (bid & 7) * (B_ * XPB / 8) + (bid >> 3);
  int b = swz / XPB, px0 = (swz % XPB) * 64;
  int tid = threadIdx.x;
  int lane = tid & 63, wv = tid >> 6;
  int lr = lane & 15, lk = lane >> 4;

  const float* xb = x + (size_t)b * C_ * HW_ + px0 + lane;
  for (int c = wv; c < C_; c += 4) t[lane][c] = xb[(size_t)c * HW_];
  __syncthreads();

  // xT write
  _Float16* ob = xT + ((size_t)b * HW_ + px0) * C_;
#pragma unroll
  for (int k = 0; k < 4; ++k) {
    int cid = tid + 256 * k;
    int px = cid >> 4, part = cid & 15;
    f16x8 v;
#pragma unroll
    for (int j = 0; j < 8; ++j) v[j] = (_Float16)t[px][part * 8 + j];
    *(f16x8*)&ob[(size_t)px * C_ + part * 8] = v;
  }

  // off1 MFMA: wave wv owns px rows wv*16..wv*16+15 (M=16, N=32, K=128)
  f32x4 acc[2];
  acc[0] = (f32x4){0.f, 0.f, 0.f, 0.f};
  acc[1] = (f32x4){0.f, 0.f, 0.f, 0.f};
#pragma unroll
  for (int kk = 0; kk < 4; ++kk) {
    f16x8 afr;
#pragma unroll
    for (int j = 0; j < 8; ++j)
      afr[j] = (_Float16)t[wv * 16 + lr][kk * 32 + lk * 8 + j];
#pragma unroll
    for (int nt = 0; nt < 2; ++nt) {
      f16x8 bfr = *(const f16x8*)&wo1H[(nt * 16 + lr) * C_ + kk * 32 + lk * 8];
      acc[nt] = __builtin_amdgcn_mfma_f32_16x16x32_f16(afr, bfr, acc[nt], 0, 0, 0);
    }
  }
  __syncthreads();   // done reading t
  float (*cl)[65] = (float(*)[65])t;   // [32 ch][64 px] overlay
#pragma unroll
  for (int nt = 0; nt < 2; ++nt)
#pragma unroll
    for (int r = 0; r < 4; ++r)
      cl[nt * 16 + lr][wv * 16 + lk * 4 + r] = acc[nt][r];
  __syncthreads();
  {
    int px = tid >> 2, part = tid & 3;
    f16x8 v;
#pragma unroll
    for (int j = 0; j < 8; ++j)
      v[j] = (_Float16)(cl[part * 8 + j][px] + bo1[part * 8 + j]);
    *(f16x8*)&off1t[((size_t)b * HW_ + px0 + px) * 32 + part * 8] = v;
  }
}

// --- Kernel B (MFMA): 3x3 dil(2) conv -> PACKED sample records ---
__global__ __launch_bounds__(256, 4) void k_coordsm(
    const _Float16* __restrict__ off1t, const _Float16* __restrict__ wo2H,
    uint2* __restrict__ srec) {
  __shared__ float clds[32][257];
  int bid = blockIdx.x;
  int swz = (bid & 7) * (B_ * BPI / 8) + (bid >> 3);
  int b = swz / BPI, p0 = (swz % BPI) * 256;
  int tid = threadIdx.x;
  int lane = tid & 63, wv_ = tid >> 6;
  int lr = lane & 15, lk = lane >> 4;

  f32x4 acc[4][2];
#pragma unroll
  for (int mt = 0; mt < 4; ++mt)
#pragma unroll
    for (int nt = 0; nt < 2; ++nt) acc[mt][nt] = (f32x4){0.f, 0.f, 0.f, 0.f};

  const _Float16* ob = off1t + (size_t)b * HW_ * 32;
  int hh[4], ww[4];
#pragma unroll
  for (int mt = 0; mt < 4; ++mt) {
    int px = p0 + (wv_ * 4 + mt) * 16 + lr;
    hh[mt] = px / W_;
    ww[mt] = px % W_;
  }
#pragma unroll
  for (int tap = 0; tap < 9; ++tap) {
    int dy2 = (tap / 3 - 1) * 2, dx2 = (tap % 3 - 1) * 2;
    f16x8 afr[4];
#pragma unroll
    for (int mt = 0; mt < 4; ++mt) {
      int h2 = hh[mt] + dy2, w2 = ww[mt] + dx2;
      f16x8 a = {};
      if ((unsigned)h2 < (unsigned)H_ && (unsigned)w2 < (unsigned)W_)
        a = *(const f16x8*)&ob[(size_t)(h2 * W_ + w2) * 32 + lk * 8];
      afr[mt] = a;
    }
#pragma unroll
    for (int nt = 0; nt < 2; ++nt) {
      f16x8 bfr = *(const f16x8*)&wo2H[(nt * 16 + lr) * 288 + tap * 32 + lk * 8];
#pragma unroll
      for (int mt = 0; mt < 4; ++mt)
        acc[mt][nt] = __builtin_amdgcn_mfma_f32_16x16x32_f16(afr[mt], bfr,
                                                             acc[mt][nt], 0, 0, 0);
    }
  }
#pragma unroll
  for (int nt = 0; nt < 2; ++nt)
#pragma unroll
    for (int mt = 0; mt < 4; ++mt)
#pragma unroll
      for (int r = 0; r < 4; ++r)
        clds[nt * 16 + lr][(wv_ * 4 + mt) * 16 + lk * 4 + r] = acc[mt][nt][r];
  __syncthreads();

  int px = p0 + tid;
  int h = px / W_, w = px % W_;
  float cwv = (float)w + sinf((float)M_PI * (float)(w + 1) / (float)W_);
  float chv = (float)h + sinf((float)M_PI * (float)(h + 1) / (float)H_);
  uint2* sb = srec + (size_t)b * G_ * HWO_;
#pragma unroll
  for (int g = 0; g < G_; ++g) {
#pragma unroll
    for (int sh = 0; sh < S_; ++sh) {
#pragma unroll
      for (int sw = 0; sw < S_; ++sw) {
        int idx = g * 4 + sh * 2 + sw;
        float offx = clds[idx][tid] * 0.25f + (sw ? 0.25f : -0.25f);
        float offy = clds[16 + idx][tid] * 0.25f + (sh ? 0.25f : -0.25f);
        float ix = fminf(fmaxf(cwv + offx - 0.5f, 0.f), (float)(W_ - 1));
        float iy = fminf(fmaxf(chv + offy - 0.5f, 0.f), (float)(H_ - 1));
        float x0f = floorf(ix), y0f = floorf(iy);
        float wx = ix - x0f, wy = iy - y0f;
        int x0 = (int)x0f, y0 = (int)y0f;       // in [0, 95]
        unsigned dx = (x0 < W_ - 1) ? 1u : 0u;
        unsigned dy = (y0 < H_ - 1) ? 1u : 0u;
        unsigned base = (unsigned)(y0 * W_ + x0);  // < 9216 < 2^14
        unsigned short u00 = h2u((_Float16)((1.f - wx) * (1.f - wy)));
        unsigned short u01 = h2u((_Float16)(wx * (1.f - wy)));
        unsigned short u10 = h2u((_Float16)((1.f - wx) * wy));
        uint2 rec;
        rec.x = base | (dx << 14) | (dy << 15) | ((unsigned)u00 << 16);
        rec.y = (unsigned)u01 | ((unsigned)u10 << 16);
        sb[(size_t)g * HWO_ + (2 * h + sh) * WO_ + (2 * w + sw)] = rec;
      }
    }
  }
}

// --- Kernel S: grid_sample + dw3x3+BN+ReLU, ONE g PER BLOCK (grid x4) ---
// 9216 blocks = exactly 6 full co-residency waves at 6 blocks/CU (no ragged
// tail); 2 barriers/block; 4 g-blocks of a tile are swizzle-adjacent -> same
// XCD, concurrent -> share xT lines in L2.
__global__ __launch_bounds__(256, 6) void k_sample(
    const _Float16* __restrict__ xT, const uint2* __restrict__ srec,
    const _Float16* __restrict__ wdwSh, const _Float16* __restrict__ bias2h,
    _Float16* __restrict__ y, int b0, int nimg) {
  __shared__ __align__(16) _Float16 up4[4 * NPOS * 8 + 832];  // 23424 B

  int NWG = nimg * TILES * 4;
  int bid = blockIdx.x;
  int swz = (bid & 7) * (NWG >> 3) + (bid >> 3);  // NWG % 8 == 0 always
  int tl = swz >> 2, g = swz & 3;   // g in low bits: same-tile g's adjacent
  int bl = tl / TILES;
  int b = b0 + bl;
  int t = tl % TILES;
  int oh0 = (t / (WO_ / TW_)) * TH_;
  int ow0 = (t % (WO_ / TW_)) * TW_;
  int tid = threadIdx.x;
  int py = tid >> 5, px = tid & 31;
  int p_out = (oh0 + py) * WO_ + ow0 + px;

  const uint2* sbase = srec + ((size_t)b * G_ + g) * HWO_;
  const _Float16* xg = xT + (size_t)b * HW_ * C_ + g * CPG_;
  // ---- sampling: 6 statically-unrolled BRANCHLESS rounds ----
#pragma unroll
  for (int r = 0; r < 6; ++r) {
    int wi = tid + r * 256;
    if (r == 5 && wi >= NITEM) continue;   // exec-mask guard, last round only
    int p = wi >> 2, cq = wi & 3;
    int hy = oh0 + p / HALO_W - 1;
    int hx = ow0 + p % HALO_W - 1;
    bool inb = ((unsigned)hy < (unsigned)HO_) && ((unsigned)hx < (unsigned)WO_);
    int hyc = min(max(hy, 0), HO_ - 1);
    int hxc = min(max(hx, 0), WO_ - 1);
    uint2 rc = sbase[(size_t)hyc * WO_ + hxc];
    int base = rc.x & 0x3FFFu;
    int dxC = ((rc.x >> 14) & 1u) << 7;            // dx * 128
    int dyC = ((rc.x >> 15) & 1u) * 12288;         // dy * 96 * 128
    _Float16 w00 = u2h((unsigned short)(rc.x >> 16));
    _Float16 w01 = u2h((unsigned short)(rc.y & 0xffffu));
    _Float16 w10 = u2h((unsigned short)(rc.y >> 16));
    float w11f = 1.f - (float)w00 - (float)w01 - (float)w10;
    const _Float16* a00p = xg + cq * 8 + (size_t)base * C_;
    f16x8 a00 = *(const f16x8*)a00p;
    f16x8 a01 = *(const f16x8*)(a00p + dxC);
    f16x8 a10 = *(const f16x8*)(a00p + dyC);
    f16x8 a11 = *(const f16x8*)(a00p + dyC + dxC);
    f16x8 v = a00 * splat8(w00) + a01 * splat8(w01) + a10 * splat8(w10) +
              a11 * splat8((_Float16)w11f);        // v_pk_fma_f16
    if (!inb) v = (f16x8){};                       // select-zero (no branch)
    *(f16x8*)&up4[((size_t)cq * NPOS + p) * 8] = v;  // aligned b128 store
  }
  __syncthreads();

  // ---- dw3x3+BN+ReLU: packed fp16 accumulation (v_pk_fma_f16) ----
#pragma unroll
  for (int q = 0; q < 4; ++q) {
    f16x8 acc = *(const f16x8*)&bias2h[g * CPG_ + q * 8];   // uniform s_load
#pragma unroll
    for (int tt = 0; tt < 9; ++tt) {
      int dy = tt / 3, dx = tt % 3;
      f16x8 pk = *(const f16x8*)
          &up4[((size_t)q * NPOS + (py + dy) * HALO_W + px + dx) * 8];
      f16x8 wv = *(const f16x8*)&wdwSh[tt * C_ + g * CPG_ + q * 8];  // s_load
      acc += pk * wv;   // 4x v_pk_fma_f16
    }
    f16x8 yv;
#pragma unroll
    for (int j = 0; j < 8; ++j)
      yv[j] = acc[j] > (_Float16)0.f ? acc[j] : (_Float16)0.f;  // pk_max
    // y quarter-plane layout: lanes write 16B contiguous (full lines)
    *(f16x8*)&y[(((size_t)(bl * G_ + g) * 4 + q) * HWO_ + p_out) * 8] = yv;
  }
}

// --- Kernel G: streaming GEMM y @ W[128][64] -> out, REVERSED image order ---
// k_sample just wrote y[last] most recently; reading images in reverse makes
// most y reads hit the 256 MB memory-side L3 instead of HBM.
__global__ __launch_bounds__(256, 4) void k_gemm(
    const _Float16* __restrict__ y, const _Float16* __restrict__ wpwH,
    const float* __restrict__ bpw, float* __restrict__ out, int b0, int nimg) {
  __shared__ float clds16[16][257];

  int NWG = nimg * TILES;
  int bid = blockIdx.x;
  int swz = (bid & 7) * (NWG >> 3) + (bid >> 3);
  int bl = (nimg - 1) - swz / TILES;   // reverse image order (L3-hot first)
  int b = b0 + bl;
  int p0 = (swz % TILES) * 256;
  int tid = threadIdx.x;
  int lane = tid & 63, wv_ = tid >> 6;
  int lr = lane & 15, lk = lane >> 4;

  f32x4 acc[4][4];
#pragma unroll
  for (int mt = 0; mt < 4; ++mt)
#pragma unroll
    for (int nt = 0; nt < 4; ++nt) acc[mt][nt] = (f32x4){0.f, 0.f, 0.f, 0.f};

  const _Float16* ybl = y + (size_t)bl * IMG_YF16;
#pragma unroll
  for (int kk = 0; kk < 4; ++kk) {
    f16x8 afr[4];
#pragma unroll
    for (int mt = 0; mt < 4; ++mt)
      afr[mt] = *(const f16x8*)&ybl[(((size_t)(kk * 4 + lk) * HWO_) + p0 +
                                     (wv_ * 4 + mt) * 16 + lr) * 8];
#pragma unroll
    for (int nt = 0; nt < 4; ++nt) {
      f16x8 bfr = *(const f16x8*)&wpwH[(nt * 16 + lr) * C_ + kk * CPG_ + lk * 8];
#pragma unroll
      for (int mt = 0; mt < 4; ++mt)
        acc[mt][nt] = __builtin_amdgcn_mfma_f32_16x16x32_f16(afr[mt], bfr,
                                                             acc[mt][nt], 0, 0, 0);
    }
  }
#pragma unroll
  for (int hq = 0; hq < 4; ++hq) {
    if (hq) __syncthreads();
#pragma unroll
    for (int mt = 0; mt < 4; ++mt) {
#pragma unroll
      for (int r = 0; r < 4; ++r)
        clds16[lr][(wv_ * 4 + mt) * 16 + lk * 4 + r] = acc[mt][hq][r];
    }
    __syncthreads();
#pragma unroll
    for (int i = 0; i < 16; ++i) {
      int o = hq * 16 + i;
      out[((size_t)b * COUT_ + o) * HWO_ + p0 + tid] = clds16[i][tid] + bpw[o];
    }
  }
}

extern "C" void kernel_launch(void* const* d_in, const int* in_sizes, int n_in,
                              void* d_out, int out_size, void* d_ws, size_t ws_size,
                              hipStream_t stream) {
  const float* x        = (const float*)d_in[0];
  const float* Wo1      = (const float*)d_in[1];
  const float* bo1      = (const float*)d_in[2];
  const float* Wo2      = (const float*)d_in[3];
  const float* Wdw      = (const float*)d_in[4];
  const float* bn_gamma = (const float*)d_in[5];
  const float* bn_beta  = (const float*)d_in[6];
  const float* bn_mean  = (const float*)d_in[7];
  const float* bn_var   = (const float*)d_in[8];
  const float* Wpw      = (const float*)d_in[9];
  const float* bpw      = (const float*)d_in[10];
  float* out = (float*)d_out;

  float* ws = (float*)d_ws;
  _Float16* xT     = (_Float16*)(ws + WS_XT);
  _Float16* off1t  = (_Float16*)(ws + WS_OFF1T);
  uint2* srec      = (uint2*)(ws + WS_SREC);
  _Float16* wpwH   = (_Float16*)(ws + WS_WPWH);
  _Float16* wo1H   = (_Float16*)(ws + WS_WO1H);
  _Float16* wo2H   = (_Float16*)(ws + WS_WO2H);
  _Float16* wdwSh  = (_Float16*)(ws + WS_WDWSH);
  _Float16* bias2h = (_Float16*)(ws + WS_BIAS2H);

  // y tiers: full/mid use dedicated region; small tier (1 img) aliases
  // off1t (dead after k_coordsm; 1-img y fits in off1t region exactly).
  int chunk;
  _Float16* yb;
  if (ws_size >= NEED_FULL)      { chunk = 16; yb = (_Float16*)(ws + WS_Y); }
  else if (ws_size >= NEED_MID)  { chunk = 8;  yb = (_Float16*)(ws + WS_Y); }
  else                           { chunk = 1;  yb = (_Float16*)(ws + WS_OFF1T); }

  k_prep   <<<(PREP_N + 255) / 256, 256, 0, stream>>>(
      Wpw, Wo1, Wo2, Wdw, bn_gamma, bn_beta, bn_mean, bn_var,
      wpwH, wo1H, wo2H, wdwSh, bias2h);
  k_xoff   <<<B_ * XPB, 256, 0, stream>>>(x, wo1H, bo1, xT, off1t);
  k_coordsm<<<B_ * BPI, 256, 0, stream>>>(off1t, wo2H, srec);
  for (int c0 = 0; c0 < B_; c0 += chunk) {
    k_sample<<<chunk * TILES * 4, 256, 0, stream>>>(xT, srec, wdwSh, bias2h,
                                                    yb, c0, chunk);
    k_gemm  <<<chunk * TILES, 256, 0, stream>>>(yb, wpwH, bpw, out, c0, chunk);
  }
}